// Round 8
// baseline (1438.000 us; speedup 1.0000x reference)
//
#include <hip/hip_runtime.h>
#include <stdint.h>

#define B_ 2
#define S_ 4096
#define D_ 1024
#define H_ 16
#define DH_ 64
#define M_ 8192

typedef __attribute__((ext_vector_type(8))) short short8;   // 8 x bf16 MFMA frag
typedef __attribute__((ext_vector_type(4))) float f32x4;    // 16x16 MFMA accumulator
typedef __attribute__((ext_vector_type(16))) float f32x16;  // 32x32 MFMA accumulator
typedef __attribute__((ext_vector_type(2))) unsigned int uint2v;
typedef __attribute__((ext_vector_type(4))) unsigned int uint4v;

__device__ __forceinline__ unsigned short f2bf(float f) {
  union { float f; unsigned int u; } v; v.f = f;
  return (unsigned short)((v.u + 0x7FFFu + ((v.u >> 16) & 1u)) >> 16);  // RNE
}

__device__ __forceinline__ unsigned int cvtpk_bf16(float lo, float hi) {
  unsigned int r;
  asm("v_cvt_pk_bf16_f32 %0, %1, %2" : "=v"(r) : "v"(lo), "v"(hi));
  return r;
}

__device__ __forceinline__ void gld_lds16(const void* g, void* l) {
  __builtin_amdgcn_global_load_lds(
      (const __attribute__((address_space(1))) void*)g,
      (__attribute__((address_space(3))) void*)l, 16, 0, 0);
}

// ---------- x (fp32) -> bf16, vectorized ----------
__global__ void conv_x(const float* __restrict__ X, unsigned short* __restrict__ Xb) {
  size_t i = ((size_t)blockIdx.x * 256 + threadIdx.x) * 8;
  float4 a = *(const float4*)(X + i);
  float4 b = *(const float4*)(X + i + 4);
  uint4 pk;
  pk.x = (unsigned int)f2bf(a.x) | ((unsigned int)f2bf(a.y) << 16);
  pk.y = (unsigned int)f2bf(a.z) | ((unsigned int)f2bf(a.w) << 16);
  pk.z = (unsigned int)f2bf(b.x) | ((unsigned int)f2bf(b.y) << 16);
  pk.w = (unsigned int)f2bf(b.z) | ((unsigned int)f2bf(b.w) << 16);
  *(uint4*)(Xb + i) = pk;
}

// ---------- w[k][n] fp32 -> wT[n][k] bf16 ----------
__global__ void conv_w(const float* __restrict__ W0, const float* __restrict__ W1,
                       const float* __restrict__ W2, const float* __restrict__ W3,
                       unsigned short* __restrict__ T0, unsigned short* __restrict__ T1,
                       unsigned short* __restrict__ T2, unsigned short* __restrict__ T3) {
  int z = blockIdx.y;
  const float* W = (z == 0) ? W0 : (z == 1) ? W1 : (z == 2) ? W2 : W3;
  unsigned short* T = (z == 0) ? T0 : (z == 1) ? T1 : (z == 2) ? T2 : T3;
  int o = blockIdx.x * 256 + threadIdx.x;
  int nn = o >> 7;
  int k0 = (o & 127) * 8;
  unsigned short t[8];
  #pragma unroll
  for (int i = 0; i < 8; ++i) t[i] = f2bf(W[(size_t)(k0 + i) * D_ + nn]);
  uint4 pk;
  pk.x = (unsigned int)t[0] | ((unsigned int)t[1] << 16);
  pk.y = (unsigned int)t[2] | ((unsigned int)t[3] << 16);
  pk.z = (unsigned int)t[4] | ((unsigned int)t[5] << 16);
  pk.w = (unsigned int)t[6] | ((unsigned int)t[7] << 16);
  *(uint4*)(T + (size_t)nn * D_ + k0) = pk;
}

// ---------- QKV projection GEMM ----------
// Q: row-major [bh][s][64], pre-scaled by (1/8)*log2(e)  (log2-domain softmax).
// K: fragment-major for the attn QK^T A-operand.
// V: fragment-major for the attn PV A-operand (V^T rows).
__global__ __launch_bounds__(256, 2)
void gemm_qkv(const unsigned short* __restrict__ Xb,
              const unsigned short* __restrict__ Wq,
              const unsigned short* __restrict__ Wk,
              const unsigned short* __restrict__ Wv,
              unsigned short* __restrict__ Qb,
              unsigned short* __restrict__ Kb,
              unsigned short* __restrict__ Vtb) {
  __shared__ char As[16384];
  __shared__ char Bs[16384];
  const int tid = threadIdx.x, wave = tid >> 6, lane = tid & 63;
  const int lg = lane >> 4, ll = lane & 15;
  const int m0 = blockIdx.x * 128, n0 = blockIdx.y * 128, z = blockIdx.z;
  const unsigned short* Wt = (z == 0) ? Wq : ((z == 1) ? Wk : Wv);
  const int wr = wave >> 1, wc = wave & 1;
  f32x4 acc[4][4];
  #pragma unroll
  for (int a = 0; a < 4; ++a)
    #pragma unroll
    for (int b = 0; b < 4; ++b) acc[a][b] = (f32x4){0.f, 0.f, 0.f, 0.f};

  const char* Ag = (const char*)Xb;
  const char* Bg = (const char*)Wt;
  for (int kt = 0; kt < 16; ++kt) {
    __syncthreads();
    #pragma unroll
    for (int i = 0; i < 2; ++i) {
      int s0 = wave * 256 + i * 128 + lane;
      int row0 = s0 >> 3, colb0 = (s0 & 7) * 16;
      gld_lds16(Ag + (size_t)(m0 + row0) * 2048 + kt * 128 + colb0, As + wave * 4096 + i * 2048);
      gld_lds16(Bg + (size_t)(n0 + row0) * 2048 + kt * 128 + colb0, Bs + wave * 4096 + i * 2048);
      int s1 = s0 + 64;
      int row1 = s1 >> 3, colb1 = (s1 & 7) * 16;
      gld_lds16(Ag + (size_t)(m0 + row1) * 2048 + kt * 128 + colb1, As + wave * 4096 + i * 2048 + 1024);
      gld_lds16(Bg + (size_t)(n0 + row1) * 2048 + kt * 128 + colb1, Bs + wave * 4096 + i * 2048 + 1024);
    }
    __syncthreads();
    #pragma unroll
    for (int c = 0; c < 2; ++c) {
      short8 af[4], bf[4];
      #pragma unroll
      for (int i = 0; i < 4; ++i) {
        af[i] = *(const short8*)(As + (wr * 64 + i * 16 + ll) * 128 + lg * 16 + c * 64);
        bf[i] = *(const short8*)(Bs + (wc * 64 + i * 16 + ll) * 128 + lg * 16 + c * 64);
      }
      #pragma unroll
      for (int mi = 0; mi < 4; ++mi)
        #pragma unroll
        for (int ni = 0; ni < 4; ++ni)
          acc[mi][ni] = __builtin_amdgcn_mfma_f32_16x16x32_bf16(af[mi], bf[ni], acc[mi][ni], 0, 0, 0);
    }
  }

  if (z == 0) {
    const float sc = 0.18033688011112042f;   // (1/8)*log2(e) folded into Q
    #pragma unroll
    for (int mi = 0; mi < 4; ++mi)
      #pragma unroll
      for (int ni = 0; ni < 4; ++ni)
        #pragma unroll
        for (int j = 0; j < 4; ++j) {
          int m = m0 + wr * 64 + mi * 16 + lg * 4 + j;
          int n = n0 + wc * 64 + ni * 16 + ll;
          int bh = (m >> 12) * H_ + (n >> 6);
          Qb[((size_t)bh * S_ + (m & 4095)) * DH_ + (n & 63)] = f2bf(acc[mi][ni][j] * sc);
        }
  } else if (z == 1) {
    #pragma unroll
    for (int mi = 0; mi < 4; ++mi)
      #pragma unroll
      for (int ni = 0; ni < 4; ++ni)
        #pragma unroll
        for (int j = 0; j < 4; ++j) {
          int m = m0 + wr * 64 + mi * 16 + lg * 4 + j;
          int n = n0 + wc * 64 + ni * 16 + ll;
          int s = m & 4095, d = n & 63;
          int bh = (m >> 12) * H_ + (n >> 6);
          size_t off = (size_t)bh * 262144 + (size_t)(s >> 5) * 2048 +
                       (size_t)(d >> 4) * 512 + (size_t)((d >> 3) & 1) * 256 +
                       (size_t)(s & 31) * 8 + (d & 7);
          Kb[off] = f2bf(acc[mi][ni][j]);
        }
  } else {
    #pragma unroll
    for (int mi = 0; mi < 4; ++mi)
      #pragma unroll
      for (int ni = 0; ni < 4; ++ni) {
        int mb = m0 + wr * 64 + mi * 16 + lg * 4;
        int n = n0 + wc * 64 + ni * 16 + ll;
        int s0 = mb & 4095, d = n & 63;
        int bh = (mb >> 12) * H_ + (n >> 6);
        size_t off = (size_t)bh * 262144 + (size_t)(s0 >> 5) * 2048 +
                     (size_t)((s0 >> 4) & 1) * 1024 + (size_t)(d >> 5) * 512 +
                     (size_t)((s0 >> 3) & 1) * 256 + (size_t)(d & 31) * 8 + (s0 & 7);
        uint2 pk;
        pk.x = (unsigned int)f2bf(acc[mi][ni][0]) | ((unsigned int)f2bf(acc[mi][ni][1]) << 16);
        pk.y = (unsigned int)f2bf(acc[mi][ni][2]) | ((unsigned int)f2bf(acc[mi][ni][3]) << 16);
        *(uint2*)(Vtb + off) = pk;
      }
  }
}

// ---------- flash attention: SPLIT-K, registers-only KV ----------
// 128-thr blocks = 2 independent waves over the SAME 64 q-rows; wave w handles
// keys [w*2048,(w+1)*2048). Fixed-shift softmax => partial (O,l) are additive:
// one __syncthreads + LDS elementwise combine at the end. 16 waves/CU.
__global__ __launch_bounds__(128, 4)
void attn_kernel(const unsigned short* __restrict__ Qb,
                 const unsigned short* __restrict__ Kf,
                 const unsigned short* __restrict__ Vf,
                 unsigned short* __restrict__ Ob) {
  __shared__ float cO[64][64];   // [elem][lane] partial-O combine buffer
  __shared__ float cl[2][64];    // partial-l combine
  const int wave = threadIdx.x >> 6;
  const int lane = threadIdx.x & 63;
  const int hh = lane >> 5;      // k-slice half
  const int ql = lane & 31;      // q / row index within 32

  // bijective XCD swizzle over 2048 blocks; each XCD covers 4 bh (4MB KV = L2)
  const int hw = blockIdx.x;
  const int virt = (hw & 7) * 256 + (hw >> 3);
  const int bh = virt >> 6, qblk = virt & 63;
  const int qbase = qblk * 64;

  const char* Qg = (const char*)Qb + (size_t)bh * S_ * 128;
  short8 qa[4], qb2[4];          // q-rows qbase+ql (set A), qbase+32+ql (set B)
  #pragma unroll
  for (int c = 0; c < 4; ++c) {
    qa[c]  = *(const short8*)(Qg + (size_t)(qbase + ql) * 128 + c * 32 + hh * 16);
    qb2[c] = *(const short8*)(Qg + (size_t)(qbase + 32 + ql) * 128 + c * 32 + hh * 16);
  }

  f32x16 oa0, oa1, ob0, ob1, zf;
  #pragma unroll
  for (int i = 0; i < 16; ++i) { oa0[i] = 0.f; oa1[i] = 0.f; ob0[i] = 0.f; ob1[i] = 0.f; zf[i] = 0.f; }
  float la = 0.f, lb = 0.f;

  const char* Kg = (const char*)Kf + (size_t)bh * 524288 + lane * 16;
  const char* Vg = (const char*)Vf + (size_t)bh * 524288 + lane * 16;

#define LOADK(dst, t) do { const char* p_ = Kg + (size_t)(t) * 4096; \
    dst[0] = *(const short8*)(p_); dst[1] = *(const short8*)(p_ + 1024); \
    dst[2] = *(const short8*)(p_ + 2048); dst[3] = *(const short8*)(p_ + 3072); } while (0)
#define LOADV(dst, t) do { const char* p_ = Vg + (size_t)(t) * 4096; \
    dst[0] = *(const short8*)(p_); dst[1] = *(const short8*)(p_ + 1024); \
    dst[2] = *(const short8*)(p_ + 2048); dst[3] = *(const short8*)(p_ + 3072); } while (0)

  const int t0 = wave * 64;      // this wave's key-tile range: [t0, t0+64)
  short8 kA[4], vA[4], kB[4], vB[4];
  LOADK(kA, t0); LOADV(vA, t0);
  LOADK(kB, t0 + 1); LOADV(vB, t0 + 1);

#define ITER(KR, VR, TP, PF) do { \
    f32x16 pa, pb; \
    __builtin_amdgcn_s_setprio(1); \
    pa = __builtin_amdgcn_mfma_f32_32x32x16_bf16(KR[0], qa[0], zf, 0, 0, 0); \
    pb = __builtin_amdgcn_mfma_f32_32x32x16_bf16(KR[0], qb2[0], zf, 0, 0, 0); \
    pa = __builtin_amdgcn_mfma_f32_32x32x16_bf16(KR[1], qa[1], pa, 0, 0, 0); \
    pb = __builtin_amdgcn_mfma_f32_32x32x16_bf16(KR[1], qb2[1], pb, 0, 0, 0); \
    pa = __builtin_amdgcn_mfma_f32_32x32x16_bf16(KR[2], qa[2], pa, 0, 0, 0); \
    pb = __builtin_amdgcn_mfma_f32_32x32x16_bf16(KR[2], qb2[2], pb, 0, 0, 0); \
    pa = __builtin_amdgcn_mfma_f32_32x32x16_bf16(KR[3], qa[3], pa, 0, 0, 0); \
    pb = __builtin_amdgcn_mfma_f32_32x32x16_bf16(KR[3], qb2[3], pb, 0, 0, 0); \
    __builtin_amdgcn_s_setprio(0); \
    if (PF) { LOADK(KR, TP); } \
    _Pragma("unroll") \
    for (int i = 0; i < 16; ++i) pa[i] = __builtin_amdgcn_exp2f(pa[i]); \
    uint4v pqa0, pqa1; \
    { \
      uint2v r; \
      r = __builtin_amdgcn_permlane32_swap(cvtpk_bf16(pa[0], pa[1]), cvtpk_bf16(pa[4], pa[5]), false, false); \
      pqa0.x = r[0]; pqa0.z = r[1]; \
      r = __builtin_amdgcn_permlane32_swap(cvtpk_bf16(pa[2], pa[3]), cvtpk_bf16(pa[6], pa[7]), false, false); \
      pqa0.y = r[0]; pqa0.w = r[1]; \
      r = __builtin_amdgcn_permlane32_swap(cvtpk_bf16(pa[8], pa[9]), cvtpk_bf16(pa[12], pa[13]), false, false); \
      pqa1.x = r[0]; pqa1.z = r[1]; \
      r = __builtin_amdgcn_permlane32_swap(cvtpk_bf16(pa[10], pa[11]), cvtpk_bf16(pa[14], pa[15]), false, false); \
      pqa1.y = r[0]; pqa1.w = r[1]; \
    } \
    _Pragma("unroll") \
    for (int i = 0; i < 16; ++i) pb[i] = __builtin_amdgcn_exp2f(pb[i]); \
    uint4v pqb0, pqb1; \
    { \
      uint2v r; \
      r = __builtin_amdgcn_permlane32_swap(cvtpk_bf16(pb[0], pb[1]), cvtpk_bf16(pb[4], pb[5]), false, false); \
      pqb0.x = r[0]; pqb0.z = r[1]; \
      r = __builtin_amdgcn_permlane32_swap(cvtpk_bf16(pb[2], pb[3]), cvtpk_bf16(pb[6], pb[7]), false, false); \
      pqb0.y = r[0]; pqb0.w = r[1]; \
      r = __builtin_amdgcn_permlane32_swap(cvtpk_bf16(pb[8], pb[9]), cvtpk_bf16(pb[12], pb[13]), false, false); \
      pqb1.x = r[0]; pqb1.z = r[1]; \
      r = __builtin_amdgcn_permlane32_swap(cvtpk_bf16(pb[10], pb[11]), cvtpk_bf16(pb[14], pb[15]), false, false); \
      pqb1.y = r[0]; pqb1.w = r[1]; \
    } \
    __builtin_amdgcn_s_setprio(1); \
    { \
      short8 psa = __builtin_bit_cast(short8, pqa0); \
      short8 psb = __builtin_bit_cast(short8, pqb0); \
      oa0 = __builtin_amdgcn_mfma_f32_32x32x16_bf16(VR[0], psa, oa0, 0, 0, 0); \
      oa1 = __builtin_amdgcn_mfma_f32_32x32x16_bf16(VR[1], psa, oa1, 0, 0, 0); \
      ob0 = __builtin_amdgcn_mfma_f32_32x32x16_bf16(VR[0], psb, ob0, 0, 0, 0); \
      ob1 = __builtin_amdgcn_mfma_f32_32x32x16_bf16(VR[1], psb, ob1, 0, 0, 0); \
    } \
    { \
      short8 psa = __builtin_bit_cast(short8, pqa1); \
      short8 psb = __builtin_bit_cast(short8, pqb1); \
      oa0 = __builtin_amdgcn_mfma_f32_32x32x16_bf16(VR[2], psa, oa0, 0, 0, 0); \
      oa1 = __builtin_amdgcn_mfma_f32_32x32x16_bf16(VR[3], psa, oa1, 0, 0, 0); \
      ob0 = __builtin_amdgcn_mfma_f32_32x32x16_bf16(VR[2], psb, ob0, 0, 0, 0); \
      ob1 = __builtin_amdgcn_mfma_f32_32x32x16_bf16(VR[3], psb, ob1, 0, 0, 0); \
    } \
    __builtin_amdgcn_s_setprio(0); \
    if (PF) { LOADV(VR, TP); } \
    float s0_ = ((pa[0] + pa[1]) + (pa[2] + pa[3])) + ((pa[4] + pa[5]) + (pa[6] + pa[7])); \
    float s1_ = ((pa[8] + pa[9]) + (pa[10] + pa[11])) + ((pa[12] + pa[13]) + (pa[14] + pa[15])); \
    float s2_ = ((pb[0] + pb[1]) + (pb[2] + pb[3])) + ((pb[4] + pb[5]) + (pb[6] + pb[7])); \
    float s3_ = ((pb[8] + pb[9]) + (pb[10] + pb[11])) + ((pb[12] + pb[13]) + (pb[14] + pb[15])); \
    float ra_ = s0_ + s1_, rb_ = s2_ + s3_; \
    ra_ += __shfl_xor(ra_, 32); \
    rb_ += __shfl_xor(rb_, 32); \
    la += ra_; lb += rb_; \
  } while (0)

  for (int t = 0; t < 64; t += 2) {
    ITER(kA, vA, t0 + t + 2, (t + 2 < 64));
    ITER(kB, vB, t0 + t + 3, (t + 3 < 64));
  }

  // ---- split-K combine: wave1 -> LDS, barrier, wave0 adds & writes ----
  if (wave == 1) {
    #pragma unroll
    for (int e = 0; e < 16; ++e) {
      cO[e][lane]      = oa0[e];
      cO[16 + e][lane] = oa1[e];
      cO[32 + e][lane] = ob0[e];
      cO[48 + e][lane] = ob1[e];
    }
    cl[0][lane] = la;
    cl[1][lane] = lb;
  }
  __syncthreads();
  if (wave == 0) {
    #pragma unroll
    for (int e = 0; e < 16; ++e) {
      oa0[e] += cO[e][lane];
      oa1[e] += cO[16 + e][lane];
      ob0[e] += cO[32 + e][lane];
      ob1[e] += cO[48 + e][lane];
    }
    la += cl[0][lane];
    lb += cl[1][lane];

    float inva = 1.f / la, invb = 1.f / lb;
    unsigned short* OpA = Ob + ((size_t)(bh >> 4) * S_ + qbase + ql) * D_ + (bh & 15) * DH_;
    unsigned short* OpB = Ob + ((size_t)(bh >> 4) * S_ + qbase + 32 + ql) * D_ + (bh & 15) * DH_;
    #pragma unroll
    for (int g = 0; g < 4; ++g) {
      uint2 pk2;
      pk2.x = (unsigned int)f2bf(oa0[4 * g + 0] * inva) | ((unsigned int)f2bf(oa0[4 * g + 1] * inva) << 16);
      pk2.y = (unsigned int)f2bf(oa0[4 * g + 2] * inva) | ((unsigned int)f2bf(oa0[4 * g + 3] * inva) << 16);
      *(uint2*)(OpA + g * 8 + hh * 4) = pk2;
      pk2.x = (unsigned int)f2bf(oa1[4 * g + 0] * inva) | ((unsigned int)f2bf(oa1[4 * g + 1] * inva) << 16);
      pk2.y = (unsigned int)f2bf(oa1[4 * g + 2] * inva) | ((unsigned int)f2bf(oa1[4 * g + 3] * inva) << 16);
      *(uint2*)(OpA + 32 + g * 8 + hh * 4) = pk2;
      pk2.x = (unsigned int)f2bf(ob0[4 * g + 0] * invb) | ((unsigned int)f2bf(ob0[4 * g + 1] * invb) << 16);
      pk2.y = (unsigned int)f2bf(ob0[4 * g + 2] * invb) | ((unsigned int)f2bf(ob0[4 * g + 3] * invb) << 16);
      *(uint2*)(OpB + g * 8 + hh * 4) = pk2;
      pk2.x = (unsigned int)f2bf(ob1[4 * g + 0] * invb) | ((unsigned int)f2bf(ob1[4 * g + 1] * invb) << 16);
      pk2.y = (unsigned int)f2bf(ob1[4 * g + 2] * invb) | ((unsigned int)f2bf(ob1[4 * g + 3] * invb) << 16);
      *(uint2*)(OpB + 32 + g * 8 + hh * 4) = pk2;
    }
  }
#undef LOADK
#undef LOADV
#undef ITER
}

// ---------- output projection GEMM: out(fp32) = Ob[8192x1024] @ w_o ----------
__global__ __launch_bounds__(256, 2)
void gemm_o(const unsigned short* __restrict__ Ab,
            const unsigned short* __restrict__ Wo,
            float* __restrict__ Out) {
  __shared__ char As[16384];
  __shared__ char Bs[16384];
  const int tid = threadIdx.x, wave = tid >> 6, lane = tid & 63;
  const int lg = lane >> 4, ll = lane & 15;
  const int m0 = blockIdx.x * 128, n0 = blockIdx.y * 128;
  const int wr = wave >> 1, wc = wave & 1;
  f32x4 acc[4][4];
  #pragma unroll
  for (int a = 0; a < 4; ++a)
    #pragma unroll
    for (int b = 0; b < 4; ++b) acc[a][b] = (f32x4){0.f, 0.f, 0.f, 0.f};

  const char* Ag = (const char*)Ab;
  const char* Bg = (const char*)Wo;
  for (int kt = 0; kt < 16; ++kt) {
    __syncthreads();
    #pragma unroll
    for (int i = 0; i < 4; ++i) {
      int s = wave * 256 + i * 64 + lane;
      int row = s >> 3, colb = (s & 7) * 16;
      gld_lds16(Ag + (size_t)(m0 + row) * 2048 + kt * 128 + colb, As + wave * 4096 + i * 1024);
      gld_lds16(Bg + (size_t)(n0 + row) * 2048 + kt * 128 + colb, Bs + wave * 4096 + i * 1024);
    }
    __syncthreads();
    #pragma unroll
    for (int c = 0; c < 2; ++c) {
      short8 af[4], bf[4];
      #pragma unroll
      for (int i = 0; i < 4; ++i) {
        af[i] = *(const short8*)(As + (wr * 64 + i * 16 + ll) * 128 + lg * 16 + c * 64);
        bf[i] = *(const short8*)(Bs + (wc * 64 + i * 16 + ll) * 128 + lg * 16 + c * 64);
      }
      #pragma unroll
      for (int mi = 0; mi < 4; ++mi)
        #pragma unroll
        for (int ni = 0; ni < 4; ++ni)
          acc[mi][ni] = __builtin_amdgcn_mfma_f32_16x16x32_bf16(af[mi], bf[ni], acc[mi][ni], 0, 0, 0);
    }
  }
  #pragma unroll
  for (int mi = 0; mi < 4; ++mi)
    #pragma unroll
    for (int ni = 0; ni < 4; ++ni)
      #pragma unroll
      for (int j = 0; j < 4; ++j) {
        int m = m0 + wr * 64 + mi * 16 + lg * 4 + j;
        int n = n0 + wc * 64 + ni * 16 + ll;
        Out[(size_t)m * D_ + n] = acc[mi][ni][j];
      }
}

extern "C" void kernel_launch(void* const* d_in, const int* in_sizes, int n_in,
                              void* d_out, int out_size, void* d_ws, size_t ws_size,
                              hipStream_t stream) {
  const float* x  = (const float*)d_in[0];
  const float* wq = (const float*)d_in[1];
  const float* wk = (const float*)d_in[2];
  const float* wv = (const float*)d_in[3];
  const float* wo = (const float*)d_in[4];
  float* out = (float*)d_out;
  char* ws = (char*)d_ws;

  unsigned short* Xb = (unsigned short*)(ws);
  unsigned short* Wq = (unsigned short*)(ws + (16u << 20));
  unsigned short* Wk = (unsigned short*)(ws + (18u << 20));
  unsigned short* Wv = (unsigned short*)(ws + (20u << 20));
  unsigned short* Wo = (unsigned short*)(ws + (22u << 20));
  unsigned short* Qb = (unsigned short*)(ws + (24u << 20));   // [bh][s][64] bf16 (pre-scaled)
  unsigned short* Kb = (unsigned short*)(ws + (40u << 20));   // K fragment-major, 16 MB
  unsigned short* Vt = (unsigned short*)(ws + (56u << 20));   // V fragment-major, 16 MB
  unsigned short* Ob = (unsigned short*)(ws + (72u << 20));   // [m][1024] bf16

  conv_x<<<dim3(4096), dim3(256), 0, stream>>>(x, Xb);
  conv_w<<<dim3(512, 4), dim3(256), 0, stream>>>(wq, wk, wv, wo, Wq, Wk, Wv, Wo);
  gemm_qkv<<<dim3(64, 8, 3), dim3(256), 0, stream>>>(Xb, Wq, Wk, Wv, Qb, Kb, Vt);
  attn_kernel<<<dim3(2048), dim3(128), 0, stream>>>(Qb, Kb, Vt, Ob);
  gemm_o<<<dim3(64, 8), dim3(256), 0, stream>>>(Ob, Wo, out);
}

// Round 9
// 282.280 us; speedup vs baseline: 5.0942x; 5.0942x over previous
//
#include <hip/hip_runtime.h>
#include <stdint.h>

#define B_ 2
#define S_ 4096
#define D_ 1024
#define H_ 16
#define DH_ 64
#define M_ 8192

typedef __attribute__((ext_vector_type(8))) short short8;   // 8 x bf16 MFMA frag
typedef __attribute__((ext_vector_type(4))) float f32x4;    // 16x16 MFMA accumulator
typedef __attribute__((ext_vector_type(16))) float f32x16;  // 32x32 MFMA accumulator
typedef __attribute__((ext_vector_type(2))) unsigned int uint2v;
typedef __attribute__((ext_vector_type(4))) unsigned int uint4v;

__device__ __forceinline__ unsigned short f2bf(float f) {
  union { float f; unsigned int u; } v; v.f = f;
  return (unsigned short)((v.u + 0x7FFFu + ((v.u >> 16) & 1u)) >> 16);  // RNE
}

__device__ __forceinline__ unsigned int cvtpk_bf16(float lo, float hi) {
  unsigned int r;
  asm("v_cvt_pk_bf16_f32 %0, %1, %2" : "=v"(r) : "v"(lo), "v"(hi));
  return r;
}

__device__ __forceinline__ void gld_lds16(const void* g, void* l) {
  __builtin_amdgcn_global_load_lds(
      (const __attribute__((address_space(1))) void*)g,
      (__attribute__((address_space(3))) void*)l, 16, 0, 0);
}

// ---------- x (fp32) -> bf16, vectorized ----------
__global__ void conv_x(const float* __restrict__ X, unsigned short* __restrict__ Xb) {
  size_t i = ((size_t)blockIdx.x * 256 + threadIdx.x) * 8;
  float4 a = *(const float4*)(X + i);
  float4 b = *(const float4*)(X + i + 4);
  uint4 pk;
  pk.x = (unsigned int)f2bf(a.x) | ((unsigned int)f2bf(a.y) << 16);
  pk.y = (unsigned int)f2bf(a.z) | ((unsigned int)f2bf(a.w) << 16);
  pk.z = (unsigned int)f2bf(b.x) | ((unsigned int)f2bf(b.y) << 16);
  pk.w = (unsigned int)f2bf(b.z) | ((unsigned int)f2bf(b.w) << 16);
  *(uint4*)(Xb + i) = pk;
}

// ---------- w[k][n] fp32 -> wT[n][k] bf16 ----------
__global__ void conv_w(const float* __restrict__ W0, const float* __restrict__ W1,
                       const float* __restrict__ W2, const float* __restrict__ W3,
                       unsigned short* __restrict__ T0, unsigned short* __restrict__ T1,
                       unsigned short* __restrict__ T2, unsigned short* __restrict__ T3) {
  int z = blockIdx.y;
  const float* W = (z == 0) ? W0 : (z == 1) ? W1 : (z == 2) ? W2 : W3;
  unsigned short* T = (z == 0) ? T0 : (z == 1) ? T1 : (z == 2) ? T2 : T3;
  int o = blockIdx.x * 256 + threadIdx.x;
  int nn = o >> 7;
  int k0 = (o & 127) * 8;
  unsigned short t[8];
  #pragma unroll
  for (int i = 0; i < 8; ++i) t[i] = f2bf(W[(size_t)(k0 + i) * D_ + nn]);
  uint4 pk;
  pk.x = (unsigned int)t[0] | ((unsigned int)t[1] << 16);
  pk.y = (unsigned int)t[2] | ((unsigned int)t[3] << 16);
  pk.z = (unsigned int)t[4] | ((unsigned int)t[5] << 16);
  pk.w = (unsigned int)t[6] | ((unsigned int)t[7] << 16);
  *(uint4*)(T + (size_t)nn * D_ + k0) = pk;
}

// ---------- QKV projection GEMM ----------
// Q: row-major [bh][s][64], pre-scaled by (1/8)*log2(e)  (log2-domain softmax).
// K: fragment-major for the attn QK^T A-operand.
// V: fragment-major for the attn PV A-operand (V^T rows).
__global__ __launch_bounds__(256, 2)
void gemm_qkv(const unsigned short* __restrict__ Xb,
              const unsigned short* __restrict__ Wq,
              const unsigned short* __restrict__ Wk,
              const unsigned short* __restrict__ Wv,
              unsigned short* __restrict__ Qb,
              unsigned short* __restrict__ Kb,
              unsigned short* __restrict__ Vtb) {
  __shared__ char As[16384];
  __shared__ char Bs[16384];
  const int tid = threadIdx.x, wave = tid >> 6, lane = tid & 63;
  const int lg = lane >> 4, ll = lane & 15;
  const int m0 = blockIdx.x * 128, n0 = blockIdx.y * 128, z = blockIdx.z;
  const unsigned short* Wt = (z == 0) ? Wq : ((z == 1) ? Wk : Wv);
  const int wr = wave >> 1, wc = wave & 1;
  f32x4 acc[4][4];
  #pragma unroll
  for (int a = 0; a < 4; ++a)
    #pragma unroll
    for (int b = 0; b < 4; ++b) acc[a][b] = (f32x4){0.f, 0.f, 0.f, 0.f};

  const char* Ag = (const char*)Xb;
  const char* Bg = (const char*)Wt;
  for (int kt = 0; kt < 16; ++kt) {
    __syncthreads();
    #pragma unroll
    for (int i = 0; i < 2; ++i) {
      int s0 = wave * 256 + i * 128 + lane;
      int row0 = s0 >> 3, colb0 = (s0 & 7) * 16;
      gld_lds16(Ag + (size_t)(m0 + row0) * 2048 + kt * 128 + colb0, As + wave * 4096 + i * 2048);
      gld_lds16(Bg + (size_t)(n0 + row0) * 2048 + kt * 128 + colb0, Bs + wave * 4096 + i * 2048);
      int s1 = s0 + 64;
      int row1 = s1 >> 3, colb1 = (s1 & 7) * 16;
      gld_lds16(Ag + (size_t)(m0 + row1) * 2048 + kt * 128 + colb1, As + wave * 4096 + i * 2048 + 1024);
      gld_lds16(Bg + (size_t)(n0 + row1) * 2048 + kt * 128 + colb1, Bs + wave * 4096 + i * 2048 + 1024);
    }
    __syncthreads();
    #pragma unroll
    for (int c = 0; c < 2; ++c) {
      short8 af[4], bf[4];
      #pragma unroll
      for (int i = 0; i < 4; ++i) {
        af[i] = *(const short8*)(As + (wr * 64 + i * 16 + ll) * 128 + lg * 16 + c * 64);
        bf[i] = *(const short8*)(Bs + (wc * 64 + i * 16 + ll) * 128 + lg * 16 + c * 64);
      }
      #pragma unroll
      for (int mi = 0; mi < 4; ++mi)
        #pragma unroll
        for (int ni = 0; ni < 4; ++ni)
          acc[mi][ni] = __builtin_amdgcn_mfma_f32_16x16x32_bf16(af[mi], bf[ni], acc[mi][ni], 0, 0, 0);
    }
  }

  if (z == 0) {
    const float sc = 0.18033688011112042f;   // (1/8)*log2(e) folded into Q
    #pragma unroll
    for (int mi = 0; mi < 4; ++mi)
      #pragma unroll
      for (int ni = 0; ni < 4; ++ni)
        #pragma unroll
        for (int j = 0; j < 4; ++j) {
          int m = m0 + wr * 64 + mi * 16 + lg * 4 + j;
          int n = n0 + wc * 64 + ni * 16 + ll;
          int bh = (m >> 12) * H_ + (n >> 6);
          Qb[((size_t)bh * S_ + (m & 4095)) * DH_ + (n & 63)] = f2bf(acc[mi][ni][j] * sc);
        }
  } else if (z == 1) {
    #pragma unroll
    for (int mi = 0; mi < 4; ++mi)
      #pragma unroll
      for (int ni = 0; ni < 4; ++ni)
        #pragma unroll
        for (int j = 0; j < 4; ++j) {
          int m = m0 + wr * 64 + mi * 16 + lg * 4 + j;
          int n = n0 + wc * 64 + ni * 16 + ll;
          int s = m & 4095, d = n & 63;
          int bh = (m >> 12) * H_ + (n >> 6);
          size_t off = (size_t)bh * 262144 + (size_t)(s >> 5) * 2048 +
                       (size_t)(d >> 4) * 512 + (size_t)((d >> 3) & 1) * 256 +
                       (size_t)(s & 31) * 8 + (d & 7);
          Kb[off] = f2bf(acc[mi][ni][j]);
        }
  } else {
    #pragma unroll
    for (int mi = 0; mi < 4; ++mi)
      #pragma unroll
      for (int ni = 0; ni < 4; ++ni) {
        int mb = m0 + wr * 64 + mi * 16 + lg * 4;
        int n = n0 + wc * 64 + ni * 16 + ll;
        int s0 = mb & 4095, d = n & 63;
        int bh = (mb >> 12) * H_ + (n >> 6);
        size_t off = (size_t)bh * 262144 + (size_t)(s0 >> 5) * 2048 +
                     (size_t)((s0 >> 4) & 1) * 1024 + (size_t)(d >> 5) * 512 +
                     (size_t)((s0 >> 3) & 1) * 256 + (size_t)(d & 31) * 8 + (s0 & 7);
        uint2 pk;
        pk.x = (unsigned int)f2bf(acc[mi][ni][0]) | ((unsigned int)f2bf(acc[mi][ni][1]) << 16);
        pk.y = (unsigned int)f2bf(acc[mi][ni][2]) | ((unsigned int)f2bf(acc[mi][ni][3]) << 16);
        *(uint2*)(Vtb + off) = pk;
      }
  }
}

// ---------- flash attention: SPLIT-K, registers-only KV ----------
// 128-thr blocks = 2 independent waves over the SAME 64 q-rows; wave w handles
// keys [w*2048,(w+1)*2048). Fixed-shift softmax => partial (O,l) are additive:
// one __syncthreads + LDS elementwise combine at the end. 4096 waves fill the
// 4-waves/SIMD capacity at ~120 VGPR. NOTE: launch_bounds min-waves must stay
// at 2 — R8's (128,4) capped unified VGPR at 128 and spilled to scratch (6 GB
// HBM traffic, 8.7x slowdown).
__global__ __launch_bounds__(128, 2)
void attn_kernel(const unsigned short* __restrict__ Qb,
                 const unsigned short* __restrict__ Kf,
                 const unsigned short* __restrict__ Vf,
                 unsigned short* __restrict__ Ob) {
  __shared__ float cO[64][64];   // [elem][lane] partial-O combine buffer
  __shared__ float cl[2][64];    // partial-l combine
  const int wave = threadIdx.x >> 6;
  const int lane = threadIdx.x & 63;
  const int hh = lane >> 5;      // k-slice half
  const int ql = lane & 31;      // q / row index within 32

  // bijective XCD swizzle over 2048 blocks; each XCD covers 4 bh (4MB KV = L2)
  const int hw = blockIdx.x;
  const int virt = (hw & 7) * 256 + (hw >> 3);
  const int bh = virt >> 6, qblk = virt & 63;
  const int qbase = qblk * 64;

  const char* Qg = (const char*)Qb + (size_t)bh * S_ * 128;
  short8 qa[4], qb2[4];          // q-rows qbase+ql (set A), qbase+32+ql (set B)
  #pragma unroll
  for (int c = 0; c < 4; ++c) {
    qa[c]  = *(const short8*)(Qg + (size_t)(qbase + ql) * 128 + c * 32 + hh * 16);
    qb2[c] = *(const short8*)(Qg + (size_t)(qbase + 32 + ql) * 128 + c * 32 + hh * 16);
  }

  f32x16 oa0, oa1, ob0, ob1, zf;
  #pragma unroll
  for (int i = 0; i < 16; ++i) { oa0[i] = 0.f; oa1[i] = 0.f; ob0[i] = 0.f; ob1[i] = 0.f; zf[i] = 0.f; }
  float la = 0.f, lb = 0.f;

  const char* Kg = (const char*)Kf + (size_t)bh * 524288 + lane * 16;
  const char* Vg = (const char*)Vf + (size_t)bh * 524288 + lane * 16;

#define LOADK(dst, t) do { const char* p_ = Kg + (size_t)(t) * 4096; \
    dst[0] = *(const short8*)(p_); dst[1] = *(const short8*)(p_ + 1024); \
    dst[2] = *(const short8*)(p_ + 2048); dst[3] = *(const short8*)(p_ + 3072); } while (0)
#define LOADV(dst, t) do { const char* p_ = Vg + (size_t)(t) * 4096; \
    dst[0] = *(const short8*)(p_); dst[1] = *(const short8*)(p_ + 1024); \
    dst[2] = *(const short8*)(p_ + 2048); dst[3] = *(const short8*)(p_ + 3072); } while (0)

  const int t0 = wave * 64;      // this wave's key-tile range: [t0, t0+64)
  short8 kA[4], vA[4], kB[4], vB[4];
  LOADK(kA, t0); LOADV(vA, t0);
  LOADK(kB, t0 + 1); LOADV(vB, t0 + 1);

#define ITER(KR, VR, TP, PF) do { \
    f32x16 pa, pb; \
    __builtin_amdgcn_s_setprio(1); \
    pa = __builtin_amdgcn_mfma_f32_32x32x16_bf16(KR[0], qa[0], zf, 0, 0, 0); \
    pb = __builtin_amdgcn_mfma_f32_32x32x16_bf16(KR[0], qb2[0], zf, 0, 0, 0); \
    pa = __builtin_amdgcn_mfma_f32_32x32x16_bf16(KR[1], qa[1], pa, 0, 0, 0); \
    pb = __builtin_amdgcn_mfma_f32_32x32x16_bf16(KR[1], qb2[1], pb, 0, 0, 0); \
    pa = __builtin_amdgcn_mfma_f32_32x32x16_bf16(KR[2], qa[2], pa, 0, 0, 0); \
    pb = __builtin_amdgcn_mfma_f32_32x32x16_bf16(KR[2], qb2[2], pb, 0, 0, 0); \
    pa = __builtin_amdgcn_mfma_f32_32x32x16_bf16(KR[3], qa[3], pa, 0, 0, 0); \
    pb = __builtin_amdgcn_mfma_f32_32x32x16_bf16(KR[3], qb2[3], pb, 0, 0, 0); \
    __builtin_amdgcn_s_setprio(0); \
    if (PF) { LOADK(KR, TP); } \
    _Pragma("unroll") \
    for (int i = 0; i < 16; ++i) pa[i] = __builtin_amdgcn_exp2f(pa[i]); \
    uint4v pqa0, pqa1; \
    { \
      uint2v r; \
      r = __builtin_amdgcn_permlane32_swap(cvtpk_bf16(pa[0], pa[1]), cvtpk_bf16(pa[4], pa[5]), false, false); \
      pqa0.x = r[0]; pqa0.z = r[1]; \
      r = __builtin_amdgcn_permlane32_swap(cvtpk_bf16(pa[2], pa[3]), cvtpk_bf16(pa[6], pa[7]), false, false); \
      pqa0.y = r[0]; pqa0.w = r[1]; \
      r = __builtin_amdgcn_permlane32_swap(cvtpk_bf16(pa[8], pa[9]), cvtpk_bf16(pa[12], pa[13]), false, false); \
      pqa1.x = r[0]; pqa1.z = r[1]; \
      r = __builtin_amdgcn_permlane32_swap(cvtpk_bf16(pa[10], pa[11]), cvtpk_bf16(pa[14], pa[15]), false, false); \
      pqa1.y = r[0]; pqa1.w = r[1]; \
    } \
    _Pragma("unroll") \
    for (int i = 0; i < 16; ++i) pb[i] = __builtin_amdgcn_exp2f(pb[i]); \
    uint4v pqb0, pqb1; \
    { \
      uint2v r; \
      r = __builtin_amdgcn_permlane32_swap(cvtpk_bf16(pb[0], pb[1]), cvtpk_bf16(pb[4], pb[5]), false, false); \
      pqb0.x = r[0]; pqb0.z = r[1]; \
      r = __builtin_amdgcn_permlane32_swap(cvtpk_bf16(pb[2], pb[3]), cvtpk_bf16(pb[6], pb[7]), false, false); \
      pqb0.y = r[0]; pqb0.w = r[1]; \
      r = __builtin_amdgcn_permlane32_swap(cvtpk_bf16(pb[8], pb[9]), cvtpk_bf16(pb[12], pb[13]), false, false); \
      pqb1.x = r[0]; pqb1.z = r[1]; \
      r = __builtin_amdgcn_permlane32_swap(cvtpk_bf16(pb[10], pb[11]), cvtpk_bf16(pb[14], pb[15]), false, false); \
      pqb1.y = r[0]; pqb1.w = r[1]; \
    } \
    __builtin_amdgcn_s_setprio(1); \
    { \
      short8 psa = __builtin_bit_cast(short8, pqa0); \
      short8 psb = __builtin_bit_cast(short8, pqb0); \
      oa0 = __builtin_amdgcn_mfma_f32_32x32x16_bf16(VR[0], psa, oa0, 0, 0, 0); \
      oa1 = __builtin_amdgcn_mfma_f32_32x32x16_bf16(VR[1], psa, oa1, 0, 0, 0); \
      ob0 = __builtin_amdgcn_mfma_f32_32x32x16_bf16(VR[0], psb, ob0, 0, 0, 0); \
      ob1 = __builtin_amdgcn_mfma_f32_32x32x16_bf16(VR[1], psb, ob1, 0, 0, 0); \
    } \
    { \
      short8 psa = __builtin_bit_cast(short8, pqa1); \
      short8 psb = __builtin_bit_cast(short8, pqb1); \
      oa0 = __builtin_amdgcn_mfma_f32_32x32x16_bf16(VR[2], psa, oa0, 0, 0, 0); \
      oa1 = __builtin_amdgcn_mfma_f32_32x32x16_bf16(VR[3], psa, oa1, 0, 0, 0); \
      ob0 = __builtin_amdgcn_mfma_f32_32x32x16_bf16(VR[2], psb, ob0, 0, 0, 0); \
      ob1 = __builtin_amdgcn_mfma_f32_32x32x16_bf16(VR[3], psb, ob1, 0, 0, 0); \
    } \
    __builtin_amdgcn_s_setprio(0); \
    if (PF) { LOADV(VR, TP); } \
    float s0_ = ((pa[0] + pa[1]) + (pa[2] + pa[3])) + ((pa[4] + pa[5]) + (pa[6] + pa[7])); \
    float s1_ = ((pa[8] + pa[9]) + (pa[10] + pa[11])) + ((pa[12] + pa[13]) + (pa[14] + pa[15])); \
    float s2_ = ((pb[0] + pb[1]) + (pb[2] + pb[3])) + ((pb[4] + pb[5]) + (pb[6] + pb[7])); \
    float s3_ = ((pb[8] + pb[9]) + (pb[10] + pb[11])) + ((pb[12] + pb[13]) + (pb[14] + pb[15])); \
    float ra_ = s0_ + s1_, rb_ = s2_ + s3_; \
    ra_ += __shfl_xor(ra_, 32); \
    rb_ += __shfl_xor(rb_, 32); \
    la += ra_; lb += rb_; \
  } while (0)

  for (int t = 0; t < 64; t += 2) {
    ITER(kA, vA, t0 + t + 2, (t + 2 < 64));
    ITER(kB, vB, t0 + t + 3, (t + 3 < 64));
  }

  // ---- split-K combine: wave1 -> LDS, barrier, wave0 adds & writes ----
  if (wave == 1) {
    #pragma unroll
    for (int e = 0; e < 16; ++e) {
      cO[e][lane]      = oa0[e];
      cO[16 + e][lane] = oa1[e];
      cO[32 + e][lane] = ob0[e];
      cO[48 + e][lane] = ob1[e];
    }
    cl[0][lane] = la;
    cl[1][lane] = lb;
  }
  __syncthreads();
  if (wave == 0) {
    #pragma unroll
    for (int e = 0; e < 16; ++e) {
      oa0[e] += cO[e][lane];
      oa1[e] += cO[16 + e][lane];
      ob0[e] += cO[32 + e][lane];
      ob1[e] += cO[48 + e][lane];
    }
    la += cl[0][lane];
    lb += cl[1][lane];

    float inva = 1.f / la, invb = 1.f / lb;
    unsigned short* OpA = Ob + ((size_t)(bh >> 4) * S_ + qbase + ql) * D_ + (bh & 15) * DH_;
    unsigned short* OpB = Ob + ((size_t)(bh >> 4) * S_ + qbase + 32 + ql) * D_ + (bh & 15) * DH_;
    #pragma unroll
    for (int g = 0; g < 4; ++g) {
      uint2 pk2;
      pk2.x = (unsigned int)f2bf(oa0[4 * g + 0] * inva) | ((unsigned int)f2bf(oa0[4 * g + 1] * inva) << 16);
      pk2.y = (unsigned int)f2bf(oa0[4 * g + 2] * inva) | ((unsigned int)f2bf(oa0[4 * g + 3] * inva) << 16);
      *(uint2*)(OpA + g * 8 + hh * 4) = pk2;
      pk2.x = (unsigned int)f2bf(oa1[4 * g + 0] * inva) | ((unsigned int)f2bf(oa1[4 * g + 1] * inva) << 16);
      pk2.y = (unsigned int)f2bf(oa1[4 * g + 2] * inva) | ((unsigned int)f2bf(oa1[4 * g + 3] * inva) << 16);
      *(uint2*)(OpA + 32 + g * 8 + hh * 4) = pk2;
      pk2.x = (unsigned int)f2bf(ob0[4 * g + 0] * invb) | ((unsigned int)f2bf(ob0[4 * g + 1] * invb) << 16);
      pk2.y = (unsigned int)f2bf(ob0[4 * g + 2] * invb) | ((unsigned int)f2bf(ob0[4 * g + 3] * invb) << 16);
      *(uint2*)(OpB + g * 8 + hh * 4) = pk2;
      pk2.x = (unsigned int)f2bf(ob1[4 * g + 0] * invb) | ((unsigned int)f2bf(ob1[4 * g + 1] * invb) << 16);
      pk2.y = (unsigned int)f2bf(ob1[4 * g + 2] * invb) | ((unsigned int)f2bf(ob1[4 * g + 3] * invb) << 16);
      *(uint2*)(OpB + 32 + g * 8 + hh * 4) = pk2;
    }
  }
#undef LOADK
#undef LOADV
#undef ITER
}

// ---------- output projection GEMM: out(fp32) = Ob[8192x1024] @ w_o ----------
__global__ __launch_bounds__(256, 2)
void gemm_o(const unsigned short* __restrict__ Ab,
            const unsigned short* __restrict__ Wo,
            float* __restrict__ Out) {
  __shared__ char As[16384];
  __shared__ char Bs[16384];
  const int tid = threadIdx.x, wave = tid >> 6, lane = tid & 63;
  const int lg = lane >> 4, ll = lane & 15;
  const int m0 = blockIdx.x * 128, n0 = blockIdx.y * 128;
  const int wr = wave >> 1, wc = wave & 1;
  f32x4 acc[4][4];
  #pragma unroll
  for (int a = 0; a < 4; ++a)
    #pragma unroll
    for (int b = 0; b < 4; ++b) acc[a][b] = (f32x4){0.f, 0.f, 0.f, 0.f};

  const char* Ag = (const char*)Ab;
  const char* Bg = (const char*)Wo;
  for (int kt = 0; kt < 16; ++kt) {
    __syncthreads();
    #pragma unroll
    for (int i = 0; i < 4; ++i) {
      int s = wave * 256 + i * 64 + lane;
      int row = s >> 3, colb = (s & 7) * 16;
      gld_lds16(Ag + (size_t)(m0 + row) * 2048 + kt * 128 + colb, As + wave * 4096 + i * 1024);
      gld_lds16(Bg + (size_t)(n0 + row) * 2048 + kt * 128 + colb, Bs + wave * 4096 + i * 1024);
    }
    __syncthreads();
    #pragma unroll
    for (int c = 0; c < 2; ++c) {
      short8 af[4], bf[4];
      #pragma unroll
      for (int i = 0; i < 4; ++i) {
        af[i] = *(const short8*)(As + (wr * 64 + i * 16 + ll) * 128 + lg * 16 + c * 64);
        bf[i] = *(const short8*)(Bs + (wc * 64 + i * 16 + ll) * 128 + lg * 16 + c * 64);
      }
      #pragma unroll
      for (int mi = 0; mi < 4; ++mi)
        #pragma unroll
        for (int ni = 0; ni < 4; ++ni)
          acc[mi][ni] = __builtin_amdgcn_mfma_f32_16x16x32_bf16(af[mi], bf[ni], acc[mi][ni], 0, 0, 0);
    }
  }
  #pragma unroll
  for (int mi = 0; mi < 4; ++mi)
    #pragma unroll
    for (int ni = 0; ni < 4; ++ni)
      #pragma unroll
      for (int j = 0; j < 4; ++j) {
        int m = m0 + wr * 64 + mi * 16 + lg * 4 + j;
        int n = n0 + wc * 64 + ni * 16 + ll;
        Out[(size_t)m * D_ + n] = acc[mi][ni][j];
      }
}

extern "C" void kernel_launch(void* const* d_in, const int* in_sizes, int n_in,
                              void* d_out, int out_size, void* d_ws, size_t ws_size,
                              hipStream_t stream) {
  const float* x  = (const float*)d_in[0];
  const float* wq = (const float*)d_in[1];
  const float* wk = (const float*)d_in[2];
  const float* wv = (const float*)d_in[3];
  const float* wo = (const float*)d_in[4];
  float* out = (float*)d_out;
  char* ws = (char*)d_ws;

  unsigned short* Xb = (unsigned short*)(ws);
  unsigned short* Wq = (unsigned short*)(ws + (16u << 20));
  unsigned short* Wk = (unsigned short*)(ws + (18u << 20));
  unsigned short* Wv = (unsigned short*)(ws + (20u << 20));
  unsigned short* Wo = (unsigned short*)(ws + (22u << 20));
  unsigned short* Qb = (unsigned short*)(ws + (24u << 20));   // [bh][s][64] bf16 (pre-scaled)
  unsigned short* Kb = (unsigned short*)(ws + (40u << 20));   // K fragment-major, 16 MB
  unsigned short* Vt = (unsigned short*)(ws + (56u << 20));   // V fragment-major, 16 MB
  unsigned short* Ob = (unsigned short*)(ws + (72u << 20));   // [m][1024] bf16

  conv_x<<<dim3(4096), dim3(256), 0, stream>>>(x, Xb);
  conv_w<<<dim3(512, 4), dim3(256), 0, stream>>>(wq, wk, wv, wo, Wq, Wk, Wv, Wo);
  gemm_qkv<<<dim3(64, 8, 3), dim3(256), 0, stream>>>(Xb, Wq, Wk, Wv, Qb, Kb, Vt);
  attn_kernel<<<dim3(2048), dim3(128), 0, stream>>>(Qb, Kb, Vt, Ob);
  gemm_o<<<dim3(64, 8), dim3(256), 0, stream>>>(Ob, Wo, out);
}

// Round 11
// 255.343 us; speedup vs baseline: 5.6316x; 1.1055x over previous
//
#include <hip/hip_runtime.h>
#include <stdint.h>

#define B_ 2
#define S_ 4096
#define D_ 1024
#define H_ 16
#define DH_ 64
#define M_ 8192

typedef __attribute__((ext_vector_type(8))) short short8;   // 8 x bf16 MFMA frag
typedef __attribute__((ext_vector_type(4))) float f32x4;    // 16x16 MFMA accumulator
typedef __attribute__((ext_vector_type(16))) float f32x16;  // 32x32 MFMA accumulator
typedef __attribute__((ext_vector_type(2))) unsigned int uint2v;
typedef __attribute__((ext_vector_type(4))) unsigned int uint4v;

__device__ __forceinline__ unsigned short f2bf(float f) {
  union { float f; unsigned int u; } v; v.f = f;
  return (unsigned short)((v.u + 0x7FFFu + ((v.u >> 16) & 1u)) >> 16);  // RNE
}

__device__ __forceinline__ unsigned int cvtpk_bf16(float lo, float hi) {
  unsigned int r;
  asm("v_cvt_pk_bf16_f32 %0, %1, %2" : "=v"(r) : "v"(lo), "v"(hi));
  return r;
}

__device__ __forceinline__ void gld_lds16(const void* g, void* l) {
  __builtin_amdgcn_global_load_lds(
      (const __attribute__((address_space(1))) void*)g,
      (__attribute__((address_space(3))) void*)l, 16, 0, 0);
}

// ---------- x (fp32) -> bf16, vectorized ----------
__global__ void conv_x(const float* __restrict__ X, unsigned short* __restrict__ Xb) {
  size_t i = ((size_t)blockIdx.x * 256 + threadIdx.x) * 8;
  float4 a = *(const float4*)(X + i);
  float4 b = *(const float4*)(X + i + 4);
  uint4 pk;
  pk.x = (unsigned int)f2bf(a.x) | ((unsigned int)f2bf(a.y) << 16);
  pk.y = (unsigned int)f2bf(a.z) | ((unsigned int)f2bf(a.w) << 16);
  pk.z = (unsigned int)f2bf(b.x) | ((unsigned int)f2bf(b.y) << 16);
  pk.w = (unsigned int)f2bf(b.z) | ((unsigned int)f2bf(b.w) << 16);
  *(uint4*)(Xb + i) = pk;
}

// ---------- w[k][n] fp32 -> wT[n][k] bf16 : LDS-tiled transpose ----------
// Old version issued 4.2M scalar 4B loads at 32KB lane stride (scatter-bound).
// New: 64x64 tile, coalesced float4 reads -> LDS [64][65] (pad => conflict-free
// transposed reads: bank=(c+i+r)%32 spans all 32) -> packed bf16 uint4 stores.
__global__ __launch_bounds__(256)
void conv_w(const float* __restrict__ W0, const float* __restrict__ W1,
            const float* __restrict__ W2, const float* __restrict__ W3,
            unsigned short* __restrict__ T0, unsigned short* __restrict__ T1,
            unsigned short* __restrict__ T2, unsigned short* __restrict__ T3) {
  __shared__ float tile[64][65];
  const int z = blockIdx.z;
  const float* W = (z == 0) ? W0 : (z == 1) ? W1 : (z == 2) ? W2 : W3;
  unsigned short* T = (z == 0) ? T0 : (z == 1) ? T1 : (z == 2) ? T2 : T3;
  const int k0 = blockIdx.x * 64, n0 = blockIdx.y * 64;
  const int t = threadIdx.x;
  const int r = t >> 2;          // 0..63
  const int c = (t & 3) * 16;    // 0,16,32,48

  const float* src = W + (size_t)(k0 + r) * D_ + n0 + c;
  float4 a0 = *(const float4*)(src + 0);
  float4 a1 = *(const float4*)(src + 4);
  float4 a2 = *(const float4*)(src + 8);
  float4 a3 = *(const float4*)(src + 12);
  tile[r][c + 0] = a0.x;  tile[r][c + 1] = a0.y;  tile[r][c + 2] = a0.z;  tile[r][c + 3] = a0.w;
  tile[r][c + 4] = a1.x;  tile[r][c + 5] = a1.y;  tile[r][c + 6] = a1.z;  tile[r][c + 7] = a1.w;
  tile[r][c + 8] = a2.x;  tile[r][c + 9] = a2.y;  tile[r][c + 10] = a2.z; tile[r][c + 11] = a2.w;
  tile[r][c + 12] = a3.x; tile[r][c + 13] = a3.y; tile[r][c + 14] = a3.z; tile[r][c + 15] = a3.w;
  __syncthreads();

  // thread writes T[n0+r][k0+c .. k0+c+15] (bf16, 32B, coalesced in 128B groups)
  unsigned int pk[8];
  #pragma unroll
  for (int i = 0; i < 8; ++i) {
    unsigned short lo = f2bf(tile[c + 2 * i + 0][r]);
    unsigned short hi = f2bf(tile[c + 2 * i + 1][r]);
    pk[i] = (unsigned int)lo | ((unsigned int)hi << 16);
  }
  unsigned short* dst = T + (size_t)(n0 + r) * D_ + k0 + c;
  *(uint4*)(dst + 0) = *(uint4*)&pk[0];
  *(uint4*)(dst + 8) = *(uint4*)&pk[4];
}

// ---------- QKV projection GEMM ----------
// Q: row-major [bh][s][64], pre-scaled by (1/8)*log2(e)  (log2-domain softmax).
// K: fragment-major for the attn QK^T A-operand.
// V: fragment-major for the attn PV A-operand (V^T rows).
__global__ __launch_bounds__(256, 2)
void gemm_qkv(const unsigned short* __restrict__ Xb,
              const unsigned short* __restrict__ Wq,
              const unsigned short* __restrict__ Wk,
              const unsigned short* __restrict__ Wv,
              unsigned short* __restrict__ Qb,
              unsigned short* __restrict__ Kb,
              unsigned short* __restrict__ Vtb) {
  __shared__ char As[16384];
  __shared__ char Bs[16384];
  const int tid = threadIdx.x, wave = tid >> 6, lane = tid & 63;
  const int lg = lane >> 4, ll = lane & 15;
  const int m0 = blockIdx.x * 128, n0 = blockIdx.y * 128, z = blockIdx.z;
  const unsigned short* Wt = (z == 0) ? Wq : ((z == 1) ? Wk : Wv);
  const int wr = wave >> 1, wc = wave & 1;
  f32x4 acc[4][4];
  #pragma unroll
  for (int a = 0; a < 4; ++a)
    #pragma unroll
    for (int b = 0; b < 4; ++b) acc[a][b] = (f32x4){0.f, 0.f, 0.f, 0.f};

  const char* Ag = (const char*)Xb;
  const char* Bg = (const char*)Wt;
  for (int kt = 0; kt < 16; ++kt) {
    __syncthreads();
    #pragma unroll
    for (int i = 0; i < 2; ++i) {
      int s0 = wave * 256 + i * 128 + lane;
      int row0 = s0 >> 3, colb0 = (s0 & 7) * 16;
      gld_lds16(Ag + (size_t)(m0 + row0) * 2048 + kt * 128 + colb0, As + wave * 4096 + i * 2048);
      gld_lds16(Bg + (size_t)(n0 + row0) * 2048 + kt * 128 + colb0, Bs + wave * 4096 + i * 2048);
      int s1 = s0 + 64;
      int row1 = s1 >> 3, colb1 = (s1 & 7) * 16;
      gld_lds16(Ag + (size_t)(m0 + row1) * 2048 + kt * 128 + colb1, As + wave * 4096 + i * 2048 + 1024);
      gld_lds16(Bg + (size_t)(n0 + row1) * 2048 + kt * 128 + colb1, Bs + wave * 4096 + i * 2048 + 1024);
    }
    __syncthreads();
    #pragma unroll
    for (int c = 0; c < 2; ++c) {
      short8 af[4], bf[4];
      #pragma unroll
      for (int i = 0; i < 4; ++i) {
        af[i] = *(const short8*)(As + (wr * 64 + i * 16 + ll) * 128 + lg * 16 + c * 64);
        bf[i] = *(const short8*)(Bs + (wc * 64 + i * 16 + ll) * 128 + lg * 16 + c * 64);
      }
      #pragma unroll
      for (int mi = 0; mi < 4; ++mi)
        #pragma unroll
        for (int ni = 0; ni < 4; ++ni)
          acc[mi][ni] = __builtin_amdgcn_mfma_f32_16x16x32_bf16(af[mi], bf[ni], acc[mi][ni], 0, 0, 0);
    }
  }

  if (z == 0) {
    const float sc = 0.18033688011112042f;   // (1/8)*log2(e) folded into Q
    #pragma unroll
    for (int mi = 0; mi < 4; ++mi)
      #pragma unroll
      for (int ni = 0; ni < 4; ++ni)
        #pragma unroll
        for (int j = 0; j < 4; ++j) {
          int m = m0 + wr * 64 + mi * 16 + lg * 4 + j;
          int n = n0 + wc * 64 + ni * 16 + ll;
          int bh = (m >> 12) * H_ + (n >> 6);
          Qb[((size_t)bh * S_ + (m & 4095)) * DH_ + (n & 63)] = f2bf(acc[mi][ni][j] * sc);
        }
  } else if (z == 1) {
    #pragma unroll
    for (int mi = 0; mi < 4; ++mi)
      #pragma unroll
      for (int ni = 0; ni < 4; ++ni)
        #pragma unroll
        for (int j = 0; j < 4; ++j) {
          int m = m0 + wr * 64 + mi * 16 + lg * 4 + j;
          int n = n0 + wc * 64 + ni * 16 + ll;
          int s = m & 4095, d = n & 63;
          int bh = (m >> 12) * H_ + (n >> 6);
          size_t off = (size_t)bh * 262144 + (size_t)(s >> 5) * 2048 +
                       (size_t)(d >> 4) * 512 + (size_t)((d >> 3) & 1) * 256 +
                       (size_t)(s & 31) * 8 + (d & 7);
          Kb[off] = f2bf(acc[mi][ni][j]);
        }
  } else {
    #pragma unroll
    for (int mi = 0; mi < 4; ++mi)
      #pragma unroll
      for (int ni = 0; ni < 4; ++ni) {
        int mb = m0 + wr * 64 + mi * 16 + lg * 4;
        int n = n0 + wc * 64 + ni * 16 + ll;
        int s0 = mb & 4095, d = n & 63;
        int bh = (mb >> 12) * H_ + (n >> 6);
        size_t off = (size_t)bh * 262144 + (size_t)(s0 >> 5) * 2048 +
                     (size_t)((s0 >> 4) & 1) * 1024 + (size_t)(d >> 5) * 512 +
                     (size_t)((s0 >> 3) & 1) * 256 + (size_t)(d & 31) * 8 + (s0 & 7);
        uint2 pk;
        pk.x = (unsigned int)f2bf(acc[mi][ni][0]) | ((unsigned int)f2bf(acc[mi][ni][1]) << 16);
        pk.y = (unsigned int)f2bf(acc[mi][ni][2]) | ((unsigned int)f2bf(acc[mi][ni][3]) << 16);
        *(uint2*)(Vtb + off) = pk;
      }
  }
}

// ---------- flash attention: REGISTERS-ONLY KV (R7 known-good) ----------
// 1 wave = 64 q-rows (2 acc sets) of one (b,h); KVBLK=32. K and V stored
// fragment-major, so each lane loads exactly its MFMA fragment with coalesced
// global_load_dwordx4 (1KB/wave/instr). Ping-pong register double-buffer,
// prefetch issued right after last use; compiler inserts fine-grained vmcnt.
// NOTE: do NOT pipeline P across tiles (R10: 4 live f32x16 P sets -> >256
// unified regs -> corrupted results; and T15/m253 predicts ~0 gain anyway).
__global__ __launch_bounds__(64, 2)
void attn_kernel(const unsigned short* __restrict__ Qb,
                 const unsigned short* __restrict__ Kf,
                 const unsigned short* __restrict__ Vf,
                 unsigned short* __restrict__ Ob) {
  const int lane = threadIdx.x & 63;
  const int hh = lane >> 5;      // k-slice half
  const int ql = lane & 31;      // q / row index within 32

  // bijective XCD swizzle over 2048 blocks; each XCD covers 4 bh (4MB KV = L2)
  const int hw = blockIdx.x;
  const int virt = (hw & 7) * 256 + (hw >> 3);
  const int bh = virt >> 6, qblk = virt & 63;
  const int qbase = qblk * 64;

  const char* Qg = (const char*)Qb + (size_t)bh * S_ * 128;
  short8 qa[4], qb2[4];          // q-rows qbase+ql (set A), qbase+32+ql (set B)
  #pragma unroll
  for (int c = 0; c < 4; ++c) {
    qa[c]  = *(const short8*)(Qg + (size_t)(qbase + ql) * 128 + c * 32 + hh * 16);
    qb2[c] = *(const short8*)(Qg + (size_t)(qbase + 32 + ql) * 128 + c * 32 + hh * 16);
  }

  f32x16 oa0, oa1, ob0, ob1, zf;
  #pragma unroll
  for (int i = 0; i < 16; ++i) { oa0[i] = 0.f; oa1[i] = 0.f; ob0[i] = 0.f; ob1[i] = 0.f; zf[i] = 0.f; }
  float la = 0.f, lb = 0.f;

  const char* Kg = (const char*)Kf + (size_t)bh * 524288 + lane * 16;
  const char* Vg = (const char*)Vf + (size_t)bh * 524288 + lane * 16;

#define LOADK(dst, t) do { const char* p_ = Kg + (size_t)(t) * 4096; \
    dst[0] = *(const short8*)(p_); dst[1] = *(const short8*)(p_ + 1024); \
    dst[2] = *(const short8*)(p_ + 2048); dst[3] = *(const short8*)(p_ + 3072); } while (0)
#define LOADV(dst, t) do { const char* p_ = Vg + (size_t)(t) * 4096; \
    dst[0] = *(const short8*)(p_); dst[1] = *(const short8*)(p_ + 1024); \
    dst[2] = *(const short8*)(p_ + 2048); dst[3] = *(const short8*)(p_ + 3072); } while (0)

  short8 kA[4], vA[4], kB[4], vB[4];
  LOADK(kA, 0); LOADV(vA, 0);
  LOADK(kB, 1); LOADV(vB, 1);

#define ITER(KR, VR, TP, PF) do { \
    f32x16 pa, pb; \
    __builtin_amdgcn_s_setprio(1); \
    pa = __builtin_amdgcn_mfma_f32_32x32x16_bf16(KR[0], qa[0], zf, 0, 0, 0); \
    pb = __builtin_amdgcn_mfma_f32_32x32x16_bf16(KR[0], qb2[0], zf, 0, 0, 0); \
    pa = __builtin_amdgcn_mfma_f32_32x32x16_bf16(KR[1], qa[1], pa, 0, 0, 0); \
    pb = __builtin_amdgcn_mfma_f32_32x32x16_bf16(KR[1], qb2[1], pb, 0, 0, 0); \
    pa = __builtin_amdgcn_mfma_f32_32x32x16_bf16(KR[2], qa[2], pa, 0, 0, 0); \
    pb = __builtin_amdgcn_mfma_f32_32x32x16_bf16(KR[2], qb2[2], pb, 0, 0, 0); \
    pa = __builtin_amdgcn_mfma_f32_32x32x16_bf16(KR[3], qa[3], pa, 0, 0, 0); \
    pb = __builtin_amdgcn_mfma_f32_32x32x16_bf16(KR[3], qb2[3], pb, 0, 0, 0); \
    __builtin_amdgcn_s_setprio(0); \
    if (PF) { LOADK(KR, TP); } \
    _Pragma("unroll") \
    for (int i = 0; i < 16; ++i) pa[i] = __builtin_amdgcn_exp2f(pa[i]); \
    uint4v pqa0, pqa1; \
    { \
      uint2v r; \
      r = __builtin_amdgcn_permlane32_swap(cvtpk_bf16(pa[0], pa[1]), cvtpk_bf16(pa[4], pa[5]), false, false); \
      pqa0.x = r[0]; pqa0.z = r[1]; \
      r = __builtin_amdgcn_permlane32_swap(cvtpk_bf16(pa[2], pa[3]), cvtpk_bf16(pa[6], pa[7]), false, false); \
      pqa0.y = r[0]; pqa0.w = r[1]; \
      r = __builtin_amdgcn_permlane32_swap(cvtpk_bf16(pa[8], pa[9]), cvtpk_bf16(pa[12], pa[13]), false, false); \
      pqa1.x = r[0]; pqa1.z = r[1]; \
      r = __builtin_amdgcn_permlane32_swap(cvtpk_bf16(pa[10], pa[11]), cvtpk_bf16(pa[14], pa[15]), false, false); \
      pqa1.y = r[0]; pqa1.w = r[1]; \
    } \
    _Pragma("unroll") \
    for (int i = 0; i < 16; ++i) pb[i] = __builtin_amdgcn_exp2f(pb[i]); \
    uint4v pqb0, pqb1; \
    { \
      uint2v r; \
      r = __builtin_amdgcn_permlane32_swap(cvtpk_bf16(pb[0], pb[1]), cvtpk_bf16(pb[4], pb[5]), false, false); \
      pqb0.x = r[0]; pqb0.z = r[1]; \
      r = __builtin_amdgcn_permlane32_swap(cvtpk_bf16(pb[2], pb[3]), cvtpk_bf16(pb[6], pb[7]), false, false); \
      pqb0.y = r[0]; pqb0.w = r[1]; \
      r = __builtin_amdgcn_permlane32_swap(cvtpk_bf16(pb[8], pb[9]), cvtpk_bf16(pb[12], pb[13]), false, false); \
      pqb1.x = r[0]; pqb1.z = r[1]; \
      r = __builtin_amdgcn_permlane32_swap(cvtpk_bf16(pb[10], pb[11]), cvtpk_bf16(pb[14], pb[15]), false, false); \
      pqb1.y = r[0]; pqb1.w = r[1]; \
    } \
    __builtin_amdgcn_s_setprio(1); \
    { \
      short8 psa = __builtin_bit_cast(short8, pqa0); \
      short8 psb = __builtin_bit_cast(short8, pqb0); \
      oa0 = __builtin_amdgcn_mfma_f32_32x32x16_bf16(VR[0], psa, oa0, 0, 0, 0); \
      oa1 = __builtin_amdgcn_mfma_f32_32x32x16_bf16(VR[1], psa, oa1, 0, 0, 0); \
      ob0 = __builtin_amdgcn_mfma_f32_32x32x16_bf16(VR[0], psb, ob0, 0, 0, 0); \
      ob1 = __builtin_amdgcn_mfma_f32_32x32x16_bf16(VR[1], psb, ob1, 0, 0, 0); \
    } \
    { \
      short8 psa = __builtin_bit_cast(short8, pqa1); \
      short8 psb = __builtin_bit_cast(short8, pqb1); \
      oa0 = __builtin_amdgcn_mfma_f32_32x32x16_bf16(VR[2], psa, oa0, 0, 0, 0); \
      oa1 = __builtin_amdgcn_mfma_f32_32x32x16_bf16(VR[3], psa, oa1, 0, 0, 0); \
      ob0 = __builtin_amdgcn_mfma_f32_32x32x16_bf16(VR[2], psb, ob0, 0, 0, 0); \
      ob1 = __builtin_amdgcn_mfma_f32_32x32x16_bf16(VR[3], psb, ob1, 0, 0, 0); \
    } \
    __builtin_amdgcn_s_setprio(0); \
    if (PF) { LOADV(VR, TP); } \
    float s0_ = ((pa[0] + pa[1]) + (pa[2] + pa[3])) + ((pa[4] + pa[5]) + (pa[6] + pa[7])); \
    float s1_ = ((pa[8] + pa[9]) + (pa[10] + pa[11])) + ((pa[12] + pa[13]) + (pa[14] + pa[15])); \
    float s2_ = ((pb[0] + pb[1]) + (pb[2] + pb[3])) + ((pb[4] + pb[5]) + (pb[6] + pb[7])); \
    float s3_ = ((pb[8] + pb[9]) + (pb[10] + pb[11])) + ((pb[12] + pb[13]) + (pb[14] + pb[15])); \
    float ra_ = s0_ + s1_, rb_ = s2_ + s3_; \
    ra_ += __shfl_xor(ra_, 32); \
    rb_ += __shfl_xor(rb_, 32); \
    la += ra_; lb += rb_; \
  } while (0)

  for (int t = 0; t < 128; t += 2) {
    ITER(kA, vA, t + 2, (t + 2 < 128));
    ITER(kB, vB, t + 3, (t + 3 < 128));
  }

  // ---- epilogue: lane owns q-rows qbase+ql (set A) and qbase+32+ql (set B)
  float inva = 1.f / la, invb = 1.f / lb;
  unsigned short* OpA = Ob + ((size_t)(bh >> 4) * S_ + qbase + ql) * D_ + (bh & 15) * DH_;
  unsigned short* OpB = Ob + ((size_t)(bh >> 4) * S_ + qbase + 32 + ql) * D_ + (bh & 15) * DH_;
  #pragma unroll
  for (int g = 0; g < 4; ++g) {
    uint2 pk2;
    pk2.x = (unsigned int)f2bf(oa0[4 * g + 0] * inva) | ((unsigned int)f2bf(oa0[4 * g + 1] * inva) << 16);
    pk2.y = (unsigned int)f2bf(oa0[4 * g + 2] * inva) | ((unsigned int)f2bf(oa0[4 * g + 3] * inva) << 16);
    *(uint2*)(OpA + g * 8 + hh * 4) = pk2;
    pk2.x = (unsigned int)f2bf(oa1[4 * g + 0] * inva) | ((unsigned int)f2bf(oa1[4 * g + 1] * inva) << 16);
    pk2.y = (unsigned int)f2bf(oa1[4 * g + 2] * inva) | ((unsigned int)f2bf(oa1[4 * g + 3] * inva) << 16);
    *(uint2*)(OpA + 32 + g * 8 + hh * 4) = pk2;
    pk2.x = (unsigned int)f2bf(ob0[4 * g + 0] * invb) | ((unsigned int)f2bf(ob0[4 * g + 1] * invb) << 16);
    pk2.y = (unsigned int)f2bf(ob0[4 * g + 2] * invb) | ((unsigned int)f2bf(ob0[4 * g + 3] * invb) << 16);
    *(uint2*)(OpB + g * 8 + hh * 4) = pk2;
    pk2.x = (unsigned int)f2bf(ob1[4 * g + 0] * invb) | ((unsigned int)f2bf(ob1[4 * g + 1] * invb) << 16);
    pk2.y = (unsigned int)f2bf(ob1[4 * g + 2] * invb) | ((unsigned int)f2bf(ob1[4 * g + 3] * invb) << 16);
    *(uint2*)(OpB + 32 + g * 8 + hh * 4) = pk2;
  }
#undef LOADK
#undef LOADV
#undef ITER
}

// ---------- output projection GEMM: out(fp32) = Ob[8192x1024] @ w_o ----------
__global__ __launch_bounds__(256, 2)
void gemm_o(const unsigned short* __restrict__ Ab,
            const unsigned short* __restrict__ Wo,
            float* __restrict__ Out) {
  __shared__ char As[16384];
  __shared__ char Bs[16384];
  const int tid = threadIdx.x, wave = tid >> 6, lane = tid & 63;
  const int lg = lane >> 4, ll = lane & 15;
  const int m0 = blockIdx.x * 128, n0 = blockIdx.y * 128;
  const int wr = wave >> 1, wc = wave & 1;
  f32x4 acc[4][4];
  #pragma unroll
  for (int a = 0; a < 4; ++a)
    #pragma unroll
    for (int b = 0; b < 4; ++b) acc[a][b] = (f32x4){0.f, 0.f, 0.f, 0.f};

  const char* Ag = (const char*)Ab;
  const char* Bg = (const char*)Wo;
  for (int kt = 0; kt < 16; ++kt) {
    __syncthreads();
    #pragma unroll
    for (int i = 0; i < 4; ++i) {
      int s = wave * 256 + i * 64 + lane;
      int row = s >> 3, colb = (s & 7) * 16;
      gld_lds16(Ag + (size_t)(m0 + row) * 2048 + kt * 128 + colb, As + wave * 4096 + i * 1024);
      gld_lds16(Bg + (size_t)(n0 + row) * 2048 + kt * 128 + colb, Bs + wave * 4096 + i * 1024);
    }
    __syncthreads();
    #pragma unroll
    for (int c = 0; c < 2; ++c) {
      short8 af[4], bf[4];
      #pragma unroll
      for (int i = 0; i < 4; ++i) {
        af[i] = *(const short8*)(As + (wr * 64 + i * 16 + ll) * 128 + lg * 16 + c * 64);
        bf[i] = *(const short8*)(Bs + (wc * 64 + i * 16 + ll) * 128 + lg * 16 + c * 64);
      }
      #pragma unroll
      for (int mi = 0; mi < 4; ++mi)
        #pragma unroll
        for (int ni = 0; ni < 4; ++ni)
          acc[mi][ni] = __builtin_amdgcn_mfma_f32_16x16x32_bf16(af[mi], bf[ni], acc[mi][ni], 0, 0, 0);
    }
  }
  #pragma unroll
  for (int mi = 0; mi < 4; ++mi)
    #pragma unroll
    for (int ni = 0; ni < 4; ++ni)
      #pragma unroll
      for (int j = 0; j < 4; ++j) {
        int m = m0 + wr * 64 + mi * 16 + lg * 4 + j;
        int n = n0 + wc * 64 + ni * 16 + ll;
        Out[(size_t)m * D_ + n] = acc[mi][ni][j];
      }
}

extern "C" void kernel_launch(void* const* d_in, const int* in_sizes, int n_in,
                              void* d_out, int out_size, void* d_ws, size_t ws_size,
                              hipStream_t stream) {
  const float* x  = (const float*)d_in[0];
  const float* wq = (const float*)d_in[1];
  const float* wk = (const float*)d_in[2];
  const float* wv = (const float*)d_in[3];
  const float* wo = (const float*)d_in[4];
  float* out = (float*)d_out;
  char* ws = (char*)d_ws;

  unsigned short* Xb = (unsigned short*)(ws);
  unsigned short* Wq = (unsigned short*)(ws + (16u << 20));
  unsigned short* Wk = (unsigned short*)(ws + (18u << 20));
  unsigned short* Wv = (unsigned short*)(ws + (20u << 20));
  unsigned short* Wo = (unsigned short*)(ws + (22u << 20));
  unsigned short* Qb = (unsigned short*)(ws + (24u << 20));   // [bh][s][64] bf16 (pre-scaled)
  unsigned short* Kb = (unsigned short*)(ws + (40u << 20));   // K fragment-major, 16 MB
  unsigned short* Vt = (unsigned short*)(ws + (56u << 20));   // V fragment-major, 16 MB
  unsigned short* Ob = (unsigned short*)(ws + (72u << 20));   // [m][1024] bf16

  conv_x<<<dim3(4096), dim3(256), 0, stream>>>(x, Xb);
  conv_w<<<dim3(16, 16, 4), dim3(256), 0, stream>>>(wq, wk, wv, wo, Wq, Wk, Wv, Wo);
  gemm_qkv<<<dim3(64, 8, 3), dim3(256), 0, stream>>>(Xb, Wq, Wk, Wv, Qb, Kb, Vt);
  attn_kernel<<<dim3(2048), dim3(64), 0, stream>>>(Qb, Kb, Vt, Ob);
  gemm_o<<<dim3(64, 8), dim3(256), 0, stream>>>(Ob, Wo, out);
}

// Round 12
// 248.400 us; speedup vs baseline: 5.7890x; 1.0280x over previous
//
#include <hip/hip_runtime.h>
#include <stdint.h>

#define B_ 2
#define S_ 4096
#define D_ 1024
#define H_ 16
#define DH_ 64
#define M_ 8192

typedef __attribute__((ext_vector_type(8))) short short8;   // 8 x bf16 MFMA frag
typedef __attribute__((ext_vector_type(4))) float f32x4;    // 16x16 MFMA accumulator
typedef __attribute__((ext_vector_type(16))) float f32x16;  // 32x32 MFMA accumulator
typedef __attribute__((ext_vector_type(2))) unsigned int uint2v;
typedef __attribute__((ext_vector_type(4))) unsigned int uint4v;

__device__ __forceinline__ unsigned short f2bf(float f) {
  union { float f; unsigned int u; } v; v.f = f;
  return (unsigned short)((v.u + 0x7FFFu + ((v.u >> 16) & 1u)) >> 16);  // RNE
}

__device__ __forceinline__ unsigned int cvtpk_bf16(float lo, float hi) {
  unsigned int r;
  asm("v_cvt_pk_bf16_f32 %0, %1, %2" : "=v"(r) : "v"(lo), "v"(hi));
  return r;
}

__device__ __forceinline__ void gld_lds16(const void* g, void* l) {
  __builtin_amdgcn_global_load_lds(
      (const __attribute__((address_space(1))) void*)g,
      (__attribute__((address_space(3))) void*)l, 16, 0, 0);
}

// ---------- x (fp32) -> bf16, vectorized ----------
__global__ void conv_x(const float* __restrict__ X, unsigned short* __restrict__ Xb) {
  size_t i = ((size_t)blockIdx.x * 256 + threadIdx.x) * 8;
  float4 a = *(const float4*)(X + i);
  float4 b = *(const float4*)(X + i + 4);
  uint4 pk;
  pk.x = (unsigned int)f2bf(a.x) | ((unsigned int)f2bf(a.y) << 16);
  pk.y = (unsigned int)f2bf(a.z) | ((unsigned int)f2bf(a.w) << 16);
  pk.z = (unsigned int)f2bf(b.x) | ((unsigned int)f2bf(b.y) << 16);
  pk.w = (unsigned int)f2bf(b.z) | ((unsigned int)f2bf(b.w) << 16);
  *(uint4*)(Xb + i) = pk;
}

// ---------- w[k][n] fp32 -> wT[n][k] bf16 : LDS-tiled transpose ----------
__global__ __launch_bounds__(256)
void conv_w(const float* __restrict__ W0, const float* __restrict__ W1,
            const float* __restrict__ W2, const float* __restrict__ W3,
            unsigned short* __restrict__ T0, unsigned short* __restrict__ T1,
            unsigned short* __restrict__ T2, unsigned short* __restrict__ T3) {
  __shared__ float tile[64][65];
  const int z = blockIdx.z;
  const float* W = (z == 0) ? W0 : (z == 1) ? W1 : (z == 2) ? W2 : W3;
  unsigned short* T = (z == 0) ? T0 : (z == 1) ? T1 : (z == 2) ? T2 : T3;
  const int k0 = blockIdx.x * 64, n0 = blockIdx.y * 64;
  const int t = threadIdx.x;
  const int r = t >> 2;          // 0..63
  const int c = (t & 3) * 16;    // 0,16,32,48

  const float* src = W + (size_t)(k0 + r) * D_ + n0 + c;
  float4 a0 = *(const float4*)(src + 0);
  float4 a1 = *(const float4*)(src + 4);
  float4 a2 = *(const float4*)(src + 8);
  float4 a3 = *(const float4*)(src + 12);
  tile[r][c + 0] = a0.x;  tile[r][c + 1] = a0.y;  tile[r][c + 2] = a0.z;  tile[r][c + 3] = a0.w;
  tile[r][c + 4] = a1.x;  tile[r][c + 5] = a1.y;  tile[r][c + 6] = a1.z;  tile[r][c + 7] = a1.w;
  tile[r][c + 8] = a2.x;  tile[r][c + 9] = a2.y;  tile[r][c + 10] = a2.z; tile[r][c + 11] = a2.w;
  tile[r][c + 12] = a3.x; tile[r][c + 13] = a3.y; tile[r][c + 14] = a3.z; tile[r][c + 15] = a3.w;
  __syncthreads();

  unsigned int pk[8];
  #pragma unroll
  for (int i = 0; i < 8; ++i) {
    unsigned short lo = f2bf(tile[c + 2 * i + 0][r]);
    unsigned short hi = f2bf(tile[c + 2 * i + 1][r]);
    pk[i] = (unsigned int)lo | ((unsigned int)hi << 16);
  }
  unsigned short* dst = T + (size_t)(n0 + r) * D_ + k0 + c;
  *(uint4*)(dst + 0) = *(uint4*)&pk[0];
  *(uint4*)(dst + 8) = *(uint4*)&pk[4];
}

// ---------- QKV projection GEMM: 32x32x16 MFMA + swizzled LDS (G21 pattern) ----------
// 128^2 tile, BK=64, 4 waves (2x2), per-wave 64x64 via acc[2][2] f32x16.
// Staging: linear gld_lds dest + pre-swizzled global source (byte ^ ((row&7)<<4));
// reads apply the same XOR -> ~4-way instead of 16-way bank aliasing.
// Q: row-major [bh][s][64], pre-scaled by (1/8)*log2(e).
// K/V: fragment-major (same formulas as before -> identical buffer contents).
__global__ __launch_bounds__(256, 2)
void gemm_qkv(const unsigned short* __restrict__ Xb,
              const unsigned short* __restrict__ Wq,
              const unsigned short* __restrict__ Wk,
              const unsigned short* __restrict__ Wv,
              unsigned short* __restrict__ Qb,
              unsigned short* __restrict__ Kb,
              unsigned short* __restrict__ Vtb) {
  __shared__ char As[16384];
  __shared__ char Bs[16384];
  const int tid = threadIdx.x, wave = tid >> 6, lane = tid & 63;
  const int hh = lane >> 5, l31 = lane & 31;
  const int m0 = blockIdx.x * 128, n0 = blockIdx.y * 128, z = blockIdx.z;
  const unsigned short* Wt = (z == 0) ? Wq : ((z == 1) ? Wk : Wv);
  const int wr = wave >> 1, wc = wave & 1;
  f32x16 acc[2][2];
  #pragma unroll
  for (int a = 0; a < 2; ++a)
    #pragma unroll
    for (int b = 0; b < 2; ++b)
      #pragma unroll
      for (int i = 0; i < 16; ++i) acc[a][b][i] = 0.f;

  const char* Ag = (const char*)Xb;
  const char* Bg = (const char*)Wt;
  const int sw = (((lane & 7) ^ (lane >> 3)) << 4);   // pre-swizzled source col
  const int xa = (l31 & 7) << 4;                      // read-side XOR (row&7)<<4

  for (int kt = 0; kt < 16; ++kt) {
    __syncthreads();
    #pragma unroll
    for (int i = 0; i < 4; ++i) {
      int row = wave * 32 + i * 8 + (lane >> 3);
      gld_lds16(Ag + (size_t)(m0 + row) * 2048 + kt * 128 + sw, As + wave * 4096 + i * 1024);
      gld_lds16(Bg + (size_t)(n0 + row) * 2048 + kt * 128 + sw, Bs + wave * 4096 + i * 1024);
    }
    __syncthreads();
    #pragma unroll
    for (int ks = 0; ks < 4; ++ks) {
      short8 af[2], bf[2];
      #pragma unroll
      for (int i = 0; i < 2; ++i) {
        int ra = wr * 64 + i * 32 + l31;
        af[i] = *(const short8*)(As + ra * 128 + ((ks * 32 + hh * 16) ^ xa));
        int rb = wc * 64 + i * 32 + l31;
        bf[i] = *(const short8*)(Bs + rb * 128 + ((ks * 32 + hh * 16) ^ xa));
      }
      #pragma unroll
      for (int mi = 0; mi < 2; ++mi)
        #pragma unroll
        for (int ni = 0; ni < 2; ++ni)
          acc[mi][ni] = __builtin_amdgcn_mfma_f32_32x32x16_bf16(af[mi], bf[ni], acc[mi][ni], 0, 0, 0);
    }
  }

  // D layout (verified): row = (r&3)+8*(r>>2)+4*hh, col = l31
  if (z == 0) {
    const float sc = 0.18033688011112042f;   // (1/8)*log2(e) folded into Q
    #pragma unroll
    for (int mi = 0; mi < 2; ++mi)
      #pragma unroll
      for (int ni = 0; ni < 2; ++ni)
        #pragma unroll
        for (int r = 0; r < 16; ++r) {
          int m = m0 + wr * 64 + mi * 32 + (r & 3) + 8 * (r >> 2) + 4 * hh;
          int n = n0 + wc * 64 + ni * 32 + l31;
          int bh = (m >> 12) * H_ + (n >> 6);
          Qb[((size_t)bh * S_ + (m & 4095)) * DH_ + (n & 63)] = f2bf(acc[mi][ni][r] * sc);
        }
  } else if (z == 1) {
    #pragma unroll
    for (int mi = 0; mi < 2; ++mi)
      #pragma unroll
      for (int ni = 0; ni < 2; ++ni)
        #pragma unroll
        for (int r = 0; r < 16; ++r) {
          int m = m0 + wr * 64 + mi * 32 + (r & 3) + 8 * (r >> 2) + 4 * hh;
          int n = n0 + wc * 64 + ni * 32 + l31;
          int s = m & 4095, d = n & 63;
          int bh = (m >> 12) * H_ + (n >> 6);
          size_t off = (size_t)bh * 262144 + (size_t)(s >> 5) * 2048 +
                       (size_t)(d >> 4) * 512 + (size_t)((d >> 3) & 1) * 256 +
                       (size_t)(s & 31) * 8 + (d & 7);
          Kb[off] = f2bf(acc[mi][ni][r]);
        }
  } else {
    #pragma unroll
    for (int mi = 0; mi < 2; ++mi)
      #pragma unroll
      for (int ni = 0; ni < 2; ++ni)
        #pragma unroll
        for (int g = 0; g < 4; ++g) {
          // regs 4g..4g+3 are rows 8g+4*hh+0..3 (consecutive s)
          int mb = m0 + wr * 64 + mi * 32 + 8 * g + 4 * hh;
          int n = n0 + wc * 64 + ni * 32 + l31;
          int s0 = mb & 4095, d = n & 63;
          int bh = (mb >> 12) * H_ + (n >> 6);
          size_t off = (size_t)bh * 262144 + (size_t)(s0 >> 5) * 2048 +
                       (size_t)((s0 >> 4) & 1) * 1024 + (size_t)(d >> 5) * 512 +
                       (size_t)((s0 >> 3) & 1) * 256 + (size_t)(d & 31) * 8 + (s0 & 7);
          uint2 pk;
          pk.x = (unsigned int)f2bf(acc[mi][ni][4 * g + 0]) | ((unsigned int)f2bf(acc[mi][ni][4 * g + 1]) << 16);
          pk.y = (unsigned int)f2bf(acc[mi][ni][4 * g + 2]) | ((unsigned int)f2bf(acc[mi][ni][4 * g + 3]) << 16);
          *(uint2*)(Vtb + off) = pk;
        }
  }
}

// ---------- flash attention: REGISTERS-ONLY KV (R7 known-good, FROZEN) ----------
__global__ __launch_bounds__(64, 2)
void attn_kernel(const unsigned short* __restrict__ Qb,
                 const unsigned short* __restrict__ Kf,
                 const unsigned short* __restrict__ Vf,
                 unsigned short* __restrict__ Ob) {
  const int lane = threadIdx.x & 63;
  const int hh = lane >> 5;      // k-slice half
  const int ql = lane & 31;      // q / row index within 32

  // bijective XCD swizzle over 2048 blocks; each XCD covers 4 bh (4MB KV = L2)
  const int hw = blockIdx.x;
  const int virt = (hw & 7) * 256 + (hw >> 3);
  const int bh = virt >> 6, qblk = virt & 63;
  const int qbase = qblk * 64;

  const char* Qg = (const char*)Qb + (size_t)bh * S_ * 128;
  short8 qa[4], qb2[4];          // q-rows qbase+ql (set A), qbase+32+ql (set B)
  #pragma unroll
  for (int c = 0; c < 4; ++c) {
    qa[c]  = *(const short8*)(Qg + (size_t)(qbase + ql) * 128 + c * 32 + hh * 16);
    qb2[c] = *(const short8*)(Qg + (size_t)(qbase + 32 + ql) * 128 + c * 32 + hh * 16);
  }

  f32x16 oa0, oa1, ob0, ob1, zf;
  #pragma unroll
  for (int i = 0; i < 16; ++i) { oa0[i] = 0.f; oa1[i] = 0.f; ob0[i] = 0.f; ob1[i] = 0.f; zf[i] = 0.f; }
  float la = 0.f, lb = 0.f;

  const char* Kg = (const char*)Kf + (size_t)bh * 524288 + lane * 16;
  const char* Vg = (const char*)Vf + (size_t)bh * 524288 + lane * 16;

#define LOADK(dst, t) do { const char* p_ = Kg + (size_t)(t) * 4096; \
    dst[0] = *(const short8*)(p_); dst[1] = *(const short8*)(p_ + 1024); \
    dst[2] = *(const short8*)(p_ + 2048); dst[3] = *(const short8*)(p_ + 3072); } while (0)
#define LOADV(dst, t) do { const char* p_ = Vg + (size_t)(t) * 4096; \
    dst[0] = *(const short8*)(p_); dst[1] = *(const short8*)(p_ + 1024); \
    dst[2] = *(const short8*)(p_ + 2048); dst[3] = *(const short8*)(p_ + 3072); } while (0)

  short8 kA[4], vA[4], kB[4], vB[4];
  LOADK(kA, 0); LOADV(vA, 0);
  LOADK(kB, 1); LOADV(vB, 1);

#define ITER(KR, VR, TP, PF) do { \
    f32x16 pa, pb; \
    __builtin_amdgcn_s_setprio(1); \
    pa = __builtin_amdgcn_mfma_f32_32x32x16_bf16(KR[0], qa[0], zf, 0, 0, 0); \
    pb = __builtin_amdgcn_mfma_f32_32x32x16_bf16(KR[0], qb2[0], zf, 0, 0, 0); \
    pa = __builtin_amdgcn_mfma_f32_32x32x16_bf16(KR[1], qa[1], pa, 0, 0, 0); \
    pb = __builtin_amdgcn_mfma_f32_32x32x16_bf16(KR[1], qb2[1], pb, 0, 0, 0); \
    pa = __builtin_amdgcn_mfma_f32_32x32x16_bf16(KR[2], qa[2], pa, 0, 0, 0); \
    pb = __builtin_amdgcn_mfma_f32_32x32x16_bf16(KR[2], qb2[2], pb, 0, 0, 0); \
    pa = __builtin_amdgcn_mfma_f32_32x32x16_bf16(KR[3], qa[3], pa, 0, 0, 0); \
    pb = __builtin_amdgcn_mfma_f32_32x32x16_bf16(KR[3], qb2[3], pb, 0, 0, 0); \
    __builtin_amdgcn_s_setprio(0); \
    if (PF) { LOADK(KR, TP); } \
    _Pragma("unroll") \
    for (int i = 0; i < 16; ++i) pa[i] = __builtin_amdgcn_exp2f(pa[i]); \
    uint4v pqa0, pqa1; \
    { \
      uint2v r; \
      r = __builtin_amdgcn_permlane32_swap(cvtpk_bf16(pa[0], pa[1]), cvtpk_bf16(pa[4], pa[5]), false, false); \
      pqa0.x = r[0]; pqa0.z = r[1]; \
      r = __builtin_amdgcn_permlane32_swap(cvtpk_bf16(pa[2], pa[3]), cvtpk_bf16(pa[6], pa[7]), false, false); \
      pqa0.y = r[0]; pqa0.w = r[1]; \
      r = __builtin_amdgcn_permlane32_swap(cvtpk_bf16(pa[8], pa[9]), cvtpk_bf16(pa[12], pa[13]), false, false); \
      pqa1.x = r[0]; pqa1.z = r[1]; \
      r = __builtin_amdgcn_permlane32_swap(cvtpk_bf16(pa[10], pa[11]), cvtpk_bf16(pa[14], pa[15]), false, false); \
      pqa1.y = r[0]; pqa1.w = r[1]; \
    } \
    _Pragma("unroll") \
    for (int i = 0; i < 16; ++i) pb[i] = __builtin_amdgcn_exp2f(pb[i]); \
    uint4v pqb0, pqb1; \
    { \
      uint2v r; \
      r = __builtin_amdgcn_permlane32_swap(cvtpk_bf16(pb[0], pb[1]), cvtpk_bf16(pb[4], pb[5]), false, false); \
      pqb0.x = r[0]; pqb0.z = r[1]; \
      r = __builtin_amdgcn_permlane32_swap(cvtpk_bf16(pb[2], pb[3]), cvtpk_bf16(pb[6], pb[7]), false, false); \
      pqb0.y = r[0]; pqb0.w = r[1]; \
      r = __builtin_amdgcn_permlane32_swap(cvtpk_bf16(pb[8], pb[9]), cvtpk_bf16(pb[12], pb[13]), false, false); \
      pqb1.x = r[0]; pqb1.z = r[1]; \
      r = __builtin_amdgcn_permlane32_swap(cvtpk_bf16(pb[10], pb[11]), cvtpk_bf16(pb[14], pb[15]), false, false); \
      pqb1.y = r[0]; pqb1.w = r[1]; \
    } \
    __builtin_amdgcn_s_setprio(1); \
    { \
      short8 psa = __builtin_bit_cast(short8, pqa0); \
      short8 psb = __builtin_bit_cast(short8, pqb0); \
      oa0 = __builtin_amdgcn_mfma_f32_32x32x16_bf16(VR[0], psa, oa0, 0, 0, 0); \
      oa1 = __builtin_amdgcn_mfma_f32_32x32x16_bf16(VR[1], psa, oa1, 0, 0, 0); \
      ob0 = __builtin_amdgcn_mfma_f32_32x32x16_bf16(VR[0], psb, ob0, 0, 0, 0); \
      ob1 = __builtin_amdgcn_mfma_f32_32x32x16_bf16(VR[1], psb, ob1, 0, 0, 0); \
    } \
    { \
      short8 psa = __builtin_bit_cast(short8, pqa1); \
      short8 psb = __builtin_bit_cast(short8, pqb1); \
      oa0 = __builtin_amdgcn_mfma_f32_32x32x16_bf16(VR[2], psa, oa0, 0, 0, 0); \
      oa1 = __builtin_amdgcn_mfma_f32_32x32x16_bf16(VR[3], psa, oa1, 0, 0, 0); \
      ob0 = __builtin_amdgcn_mfma_f32_32x32x16_bf16(VR[2], psb, ob0, 0, 0, 0); \
      ob1 = __builtin_amdgcn_mfma_f32_32x32x16_bf16(VR[3], psb, ob1, 0, 0, 0); \
    } \
    __builtin_amdgcn_s_setprio(0); \
    if (PF) { LOADV(VR, TP); } \
    float s0_ = ((pa[0] + pa[1]) + (pa[2] + pa[3])) + ((pa[4] + pa[5]) + (pa[6] + pa[7])); \
    float s1_ = ((pa[8] + pa[9]) + (pa[10] + pa[11])) + ((pa[12] + pa[13]) + (pa[14] + pa[15])); \
    float s2_ = ((pb[0] + pb[1]) + (pb[2] + pb[3])) + ((pb[4] + pb[5]) + (pb[6] + pb[7])); \
    float s3_ = ((pb[8] + pb[9]) + (pb[10] + pb[11])) + ((pb[12] + pb[13]) + (pb[14] + pb[15])); \
    float ra_ = s0_ + s1_, rb_ = s2_ + s3_; \
    ra_ += __shfl_xor(ra_, 32); \
    rb_ += __shfl_xor(rb_, 32); \
    la += ra_; lb += rb_; \
  } while (0)

  for (int t = 0; t < 128; t += 2) {
    ITER(kA, vA, t + 2, (t + 2 < 128));
    ITER(kB, vB, t + 3, (t + 3 < 128));
  }

  // ---- epilogue: lane owns q-rows qbase+ql (set A) and qbase+32+ql (set B)
  float inva = 1.f / la, invb = 1.f / lb;
  unsigned short* OpA = Ob + ((size_t)(bh >> 4) * S_ + qbase + ql) * D_ + (bh & 15) * DH_;
  unsigned short* OpB = Ob + ((size_t)(bh >> 4) * S_ + qbase + 32 + ql) * D_ + (bh & 15) * DH_;
  #pragma unroll
  for (int g = 0; g < 4; ++g) {
    uint2 pk2;
    pk2.x = (unsigned int)f2bf(oa0[4 * g + 0] * inva) | ((unsigned int)f2bf(oa0[4 * g + 1] * inva) << 16);
    pk2.y = (unsigned int)f2bf(oa0[4 * g + 2] * inva) | ((unsigned int)f2bf(oa0[4 * g + 3] * inva) << 16);
    *(uint2*)(OpA + g * 8 + hh * 4) = pk2;
    pk2.x = (unsigned int)f2bf(oa1[4 * g + 0] * inva) | ((unsigned int)f2bf(oa1[4 * g + 1] * inva) << 16);
    pk2.y = (unsigned int)f2bf(oa1[4 * g + 2] * inva) | ((unsigned int)f2bf(oa1[4 * g + 3] * inva) << 16);
    *(uint2*)(OpA + 32 + g * 8 + hh * 4) = pk2;
    pk2.x = (unsigned int)f2bf(ob0[4 * g + 0] * invb) | ((unsigned int)f2bf(ob0[4 * g + 1] * invb) << 16);
    pk2.y = (unsigned int)f2bf(ob0[4 * g + 2] * invb) | ((unsigned int)f2bf(ob0[4 * g + 3] * invb) << 16);
    *(uint2*)(OpB + g * 8 + hh * 4) = pk2;
    pk2.x = (unsigned int)f2bf(ob1[4 * g + 0] * invb) | ((unsigned int)f2bf(ob1[4 * g + 1] * invb) << 16);
    pk2.y = (unsigned int)f2bf(ob1[4 * g + 2] * invb) | ((unsigned int)f2bf(ob1[4 * g + 3] * invb) << 16);
    *(uint2*)(OpB + 32 + g * 8 + hh * 4) = pk2;
  }
#undef LOADK
#undef LOADV
#undef ITER
}

// ---------- output projection GEMM: 32x32x16 MFMA + swizzled LDS ----------
__global__ __launch_bounds__(256, 2)
void gemm_o(const unsigned short* __restrict__ Ab,
            const unsigned short* __restrict__ Wo,
            float* __restrict__ Out) {
  __shared__ char As[16384];
  __shared__ char Bs[16384];
  const int tid = threadIdx.x, wave = tid >> 6, lane = tid & 63;
  const int hh = lane >> 5, l31 = lane & 31;
  const int m0 = blockIdx.x * 128, n0 = blockIdx.y * 128;
  const int wr = wave >> 1, wc = wave & 1;
  f32x16 acc[2][2];
  #pragma unroll
  for (int a = 0; a < 2; ++a)
    #pragma unroll
    for (int b = 0; b < 2; ++b)
      #pragma unroll
      for (int i = 0; i < 16; ++i) acc[a][b][i] = 0.f;

  const char* Ag = (const char*)Ab;
  const char* Bg = (const char*)Wo;
  const int sw = (((lane & 7) ^ (lane >> 3)) << 4);
  const int xa = (l31 & 7) << 4;

  for (int kt = 0; kt < 16; ++kt) {
    __syncthreads();
    #pragma unroll
    for (int i = 0; i < 4; ++i) {
      int row = wave * 32 + i * 8 + (lane >> 3);
      gld_lds16(Ag + (size_t)(m0 + row) * 2048 + kt * 128 + sw, As + wave * 4096 + i * 1024);
      gld_lds16(Bg + (size_t)(n0 + row) * 2048 + kt * 128 + sw, Bs + wave * 4096 + i * 1024);
    }
    __syncthreads();
    #pragma unroll
    for (int ks = 0; ks < 4; ++ks) {
      short8 af[2], bf[2];
      #pragma unroll
      for (int i = 0; i < 2; ++i) {
        int ra = wr * 64 + i * 32 + l31;
        af[i] = *(const short8*)(As + ra * 128 + ((ks * 32 + hh * 16) ^ xa));
        int rb = wc * 64 + i * 32 + l31;
        bf[i] = *(const short8*)(Bs + rb * 128 + ((ks * 32 + hh * 16) ^ xa));
      }
      #pragma unroll
      for (int mi = 0; mi < 2; ++mi)
        #pragma unroll
        for (int ni = 0; ni < 2; ++ni)
          acc[mi][ni] = __builtin_amdgcn_mfma_f32_32x32x16_bf16(af[mi], bf[ni], acc[mi][ni], 0, 0, 0);
    }
  }
  #pragma unroll
  for (int mi = 0; mi < 2; ++mi)
    #pragma unroll
    for (int ni = 0; ni < 2; ++ni)
      #pragma unroll
      for (int r = 0; r < 16; ++r) {
        int m = m0 + wr * 64 + mi * 32 + (r & 3) + 8 * (r >> 2) + 4 * hh;
        int n = n0 + wc * 64 + ni * 32 + l31;
        Out[(size_t)m * D_ + n] = acc[mi][ni][r];
      }
}

extern "C" void kernel_launch(void* const* d_in, const int* in_sizes, int n_in,
                              void* d_out, int out_size, void* d_ws, size_t ws_size,
                              hipStream_t stream) {
  const float* x  = (const float*)d_in[0];
  const float* wq = (const float*)d_in[1];
  const float* wk = (const float*)d_in[2];
  const float* wv = (const float*)d_in[3];
  const float* wo = (const float*)d_in[4];
  float* out = (float*)d_out;
  char* ws = (char*)d_ws;

  unsigned short* Xb = (unsigned short*)(ws);
  unsigned short* Wq = (unsigned short*)(ws + (16u << 20));
  unsigned short* Wk = (unsigned short*)(ws + (18u << 20));
  unsigned short* Wv = (unsigned short*)(ws + (20u << 20));
  unsigned short* Wo = (unsigned short*)(ws + (22u << 20));
  unsigned short* Qb = (unsigned short*)(ws + (24u << 20));   // [bh][s][64] bf16 (pre-scaled)
  unsigned short* Kb = (unsigned short*)(ws + (40u << 20));   // K fragment-major, 16 MB
  unsigned short* Vt = (unsigned short*)(ws + (56u << 20));   // V fragment-major, 16 MB
  unsigned short* Ob = (unsigned short*)(ws + (72u << 20));   // [m][1024] bf16

  conv_x<<<dim3(4096), dim3(256), 0, stream>>>(x, Xb);
  conv_w<<<dim3(16, 16, 4), dim3(256), 0, stream>>>(wq, wk, wv, wo, Wq, Wk, Wv, Wo);
  gemm_qkv<<<dim3(64, 8, 3), dim3(256), 0, stream>>>(Xb, Wq, Wk, Wv, Qb, Kb, Vt);
  attn_kernel<<<dim3(2048), dim3(64), 0, stream>>>(Qb, Kb, Vt, Ob);
  gemm_o<<<dim3(64, 8), dim3(256), 0, stream>>>(Ob, Wo, out);
}